// Round 2
// baseline (2065.255 us; speedup 1.0000x reference)
//
#include <hip/hip_runtime.h>
#include <math.h>

// ---------------------------------------------------------------------------
// EquivariantNet forward — fused HIP implementation, round 2.
// Conv kernels restructured: thread = edge, oo-loop inside, weights via
// wave-uniform indices -> s_load into SGPRs (off the LDS/VMEM vector path).
// Shapes: N=8192, E=131072, C=16, Fe=16, mid=16, KV=16, ckv=8, Co=8, HEADS=4, L=2
// ---------------------------------------------------------------------------

// ---------------- CSR build over edge_dst ----------------
__global__ void k_zero(int* p, int n) {
    int i = blockIdx.x * 256 + threadIdx.x;
    if (i < n) p[i] = 0;
}

__global__ void k_hist(const int* __restrict__ dst, int* __restrict__ counts, int E) {
    int e = blockIdx.x * 256 + threadIdx.x;
    if (e < E) atomicAdd(&counts[dst[e]], 1);
}

__global__ __launch_bounds__(1024) void k_scan(const int* __restrict__ counts,
                                               int* __restrict__ rowptr,
                                               int* __restrict__ cursor,
                                               int N, int CH) {
    __shared__ int part[1024];
    int t = threadIdx.x;
    int s = 0;
    for (int i = 0; i < CH; ++i) {
        int idx = t * CH + i;
        if (idx < N) s += counts[idx];
    }
    part[t] = s;
    __syncthreads();
    for (int off = 1; off < 1024; off <<= 1) {
        int v = (t >= off) ? part[t - off] : 0;
        __syncthreads();
        part[t] += v;
        __syncthreads();
    }
    int run = (t == 0) ? 0 : part[t - 1];
    for (int i = 0; i < CH; ++i) {
        int idx = t * CH + i;
        if (idx < N) {
            rowptr[idx] = run;
            cursor[idx] = run;
            run += counts[idx];
        }
    }
    if (t == 0) rowptr[N] = part[1023];
}

__global__ void k_scatter(const int* __restrict__ dst, int* __restrict__ cursor,
                          int* __restrict__ eids, int E) {
    int e = blockIdx.x * 256 + threadIdx.x;
    if (e < E) {
        int pos = atomicAdd(&cursor[dst[e]], 1);
        eids[pos] = e;
    }
}

// ---------------- init x working copies ----------------
__global__ void k_initx(const float* __restrict__ x0, const float* __restrict__ x1,
                        float* __restrict__ xs0, float* __restrict__ xs1, int n0, int n1) {
    int i = blockIdx.x * 256 + threadIdx.x;
    if (i < n0) xs0[i] = x0[i];
    else if (i < n0 + n1) xs1[i - n0] = x1[i - n0];
}

// ---------------- conv: nf1 pairs (0->0, 0->1, 1->0) — thread = edge ----------
// Weights read via wave-uniform indices => scalar loads (SGPR), x/H in VGPRs.
template <int KVO>
__global__ __launch_bounds__(256) void k_convA(
    int E,
    const float* __restrict__ ef, const float* __restrict__ b00,
    const float* __restrict__ b01, const float* __restrict__ b10,
    const int* __restrict__ src,
    const float* __restrict__ xs0, const float* __restrict__ xs1,
    const float* __restrict__ w1,  // (3,16,16): [pp][f][h]
    const float* __restrict__ w2,  // (3,16,KVO,16): [pp][h][oo][i]
    float* __restrict__ out0,      // (E,KVO)        written (=)
    float* __restrict__ out1)      // (E,KVO,3)      written (=)
{
    int e = blockIdx.x * 256 + threadIdx.x;
    if (e >= E) return;
    int s = src[e];

    // ef[16] per-lane (4x float4, coalesced in aggregate)
    float efr[16];
    {
        const float4* p = (const float4*)(ef + (size_t)e * 16);
#pragma unroll
        for (int k = 0; k < 4; ++k) {
            float4 v = p[k];
            efr[k * 4 + 0] = v.x; efr[k * 4 + 1] = v.y;
            efr[k * 4 + 2] = v.z; efr[k * 4 + 3] = v.w;
        }
    }

    // H[pp][h] = relu(sum_f ef[f] * w1[pp][f][h])   (weights SGPR-uniform)
    float H[3][16];
#pragma unroll
    for (int pp = 0; pp < 3; ++pp) {
#pragma unroll
        for (int h = 0; h < 16; ++h) H[pp][h] = 0.f;
#pragma unroll
        for (int f = 0; f < 16; ++f) {
            const float* wrow = w1 + ((pp * 16 + f) * 16);
#pragma unroll
            for (int h = 0; h < 16; ++h) H[pp][h] += efr[f] * wrow[h];
        }
#pragma unroll
        for (int h = 0; h < 16; ++h) H[pp][h] = fmaxf(H[pp][h], 0.f);
    }

    // x0[16]
    float x0r[16];
    {
        const float4* p = (const float4*)(xs0 + (size_t)s * 16);
#pragma unroll
        for (int k = 0; k < 4; ++k) {
            float4 v = p[k];
            x0r[k * 4 + 0] = v.x; x0r[k * 4 + 1] = v.y;
            x0r[k * 4 + 2] = v.z; x0r[k * 4 + 3] = v.w;
        }
    }
    // t10[i] = sum_q b10[q] * x1[i][q]
    float t10[16];
    {
        float x1f[48];
        const float4* p = (const float4*)(xs1 + (size_t)s * 48);
#pragma unroll
        for (int k = 0; k < 12; ++k) {
            float4 v = p[k];
            x1f[k * 4 + 0] = v.x; x1f[k * 4 + 1] = v.y;
            x1f[k * 4 + 2] = v.z; x1f[k * 4 + 3] = v.w;
        }
        float bq0 = b10[e * 3 + 0], bq1 = b10[e * 3 + 1], bq2 = b10[e * 3 + 2];
#pragma unroll
        for (int i = 0; i < 16; ++i)
            t10[i] = bq0 * x1f[i * 3 + 0] + bq1 * x1f[i * 3 + 1] + bq2 * x1f[i * 3 + 2];
    }
    float b00r = b00[e];
    float b01r0 = b01[e * 3 + 0], b01r1 = b01[e * 3 + 1], b01r2 = b01[e * 3 + 2];

    for (int oo = 0; oo < KVO; ++oo) {
        float g00 = 0.f, g01 = 0.f, g10 = 0.f;
#pragma unroll
        for (int h = 0; h < 16; ++h) {
            const float* w0 = w2 + (((0 * 16 + h) * KVO + oo) * 16);
            const float* w1p = w2 + (((1 * 16 + h) * KVO + oo) * 16);
            const float* w2p = w2 + (((2 * 16 + h) * KVO + oo) * 16);
            float d0 = 0.f, d1 = 0.f, d2 = 0.f;
#pragma unroll
            for (int i = 0; i < 16; ++i) {
                d0 += w0[i] * x0r[i];
                d1 += w1p[i] * x0r[i];
                d2 += w2p[i] * t10[i];
            }
            g00 += H[0][h] * d0;
            g01 += H[1][h] * d1;
            g10 += H[2][h] * d2;
        }
        out0[(size_t)e * KVO + oo] = g00 * b00r + g10;
        size_t base = ((size_t)e * KVO + oo) * 3;
        out1[base + 0] = g01 * b01r0;
        out1[base + 1] = g01 * b01r1;
        out1[base + 2] = g01 * b01r2;
    }
}

// ---------------- conv: pair (1->1) with b11 (E,3,3,3) — thread = edge -------
template <int KVO>
__global__ __launch_bounds__(256) void k_convB(
    int E,
    const float* __restrict__ ef, const float* __restrict__ b11,
    const int* __restrict__ src, const float* __restrict__ xs1,
    const float* __restrict__ w1p3,  // (16,16) row 3: [f][h]
    const float* __restrict__ w211,  // (16,KVO,16,3): [h][oo][i][f]
    float* __restrict__ out1)        // (E,KVO,3) — accumulated (+=)
{
    int e = blockIdx.x * 256 + threadIdx.x;
    if (e >= E) return;
    int s = src[e];

    float efr[16];
    {
        const float4* p = (const float4*)(ef + (size_t)e * 16);
#pragma unroll
        for (int k = 0; k < 4; ++k) {
            float4 v = p[k];
            efr[k * 4 + 0] = v.x; efr[k * 4 + 1] = v.y;
            efr[k * 4 + 2] = v.z; efr[k * 4 + 3] = v.w;
        }
    }
    float H[16];
#pragma unroll
    for (int h = 0; h < 16; ++h) H[h] = 0.f;
#pragma unroll
    for (int f = 0; f < 16; ++f) {
        const float* wrow = w1p3 + f * 16;
#pragma unroll
        for (int h = 0; h < 16; ++h) H[h] += efr[f] * wrow[h];
    }
#pragma unroll
    for (int h = 0; h < 16; ++h) H[h] = fmaxf(H[h], 0.f);

    float x1r[48];
    {
        const float4* p = (const float4*)(xs1 + (size_t)s * 48);
#pragma unroll
        for (int k = 0; k < 12; ++k) {
            float4 v = p[k];
            x1r[k * 4 + 0] = v.x; x1r[k * 4 + 1] = v.y;
            x1r[k * 4 + 2] = v.z; x1r[k * 4 + 3] = v.w;
        }
    }
    float b11r[27];
#pragma unroll
    for (int k = 0; k < 27; ++k) b11r[k] = b11[(size_t)e * 27 + k];

    for (int oo = 0; oo < KVO; ++oo) {
        float R[48];  // [f][i] = sum_h H[h] * w211[h][oo][i][f]
#pragma unroll
        for (int k = 0; k < 48; ++k) R[k] = 0.f;
#pragma unroll
        for (int h = 0; h < 16; ++h) {
            const float* wp = w211 + ((size_t)(h * KVO + oo) * 48);  // [i*3+f]
            float hv = H[h];
#pragma unroll
            for (int i = 0; i < 16; ++i) {
                R[0 * 16 + i] += hv * wp[i * 3 + 0];
                R[1 * 16 + i] += hv * wp[i * 3 + 1];
                R[2 * 16 + i] += hv * wp[i * 3 + 2];
            }
        }
        float G[3][3];  // [q][f] = sum_i R[f][i] * x1[i][q]
#pragma unroll
        for (int q = 0; q < 3; ++q)
#pragma unroll
            for (int f = 0; f < 3; ++f) {
                float d = 0.f;
#pragma unroll
                for (int i = 0; i < 16; ++i) d += R[f * 16 + i] * x1r[i * 3 + q];
                G[q][f] = d;
            }
        size_t base = ((size_t)e * KVO + oo) * 3;
#pragma unroll
        for (int p = 0; p < 3; ++p) {
            float sum = out1[base + p];
#pragma unroll
            for (int q = 0; q < 3; ++q)
#pragma unroll
                for (int f = 0; f < 3; ++f) sum += G[q][f] * b11r[p * 9 + q * 3 + f];
            out1[base + p] = sum;
        }
    }
}

// ---------------- q projection ----------------
__global__ void k_q(int N, const float* __restrict__ xs0, const float* __restrict__ xs1,
                    const float* __restrict__ wq,  // (2,16,8) for this layer
                    float* __restrict__ q0, float* __restrict__ q1) {
    int t = blockIdx.x * 256 + threadIdx.x;
    if (t >= N * 32) return;
    int n = t >> 5, comp = t & 31;
    if (comp < 8) {
        float a = 0.f;
#pragma unroll
        for (int c = 0; c < 16; ++c) a += xs0[n * 16 + c] * wq[c * 8 + comp];
        q0[n * 8 + comp] = a;
    } else {
        int idx = comp - 8, dd = idx / 3, mm = idx % 3;
        float a = 0.f;
#pragma unroll
        for (int c = 0; c < 16; ++c) a += xs1[n * 48 + c * 3 + mm] * wq[128 + c * 8 + dd];
        q1[n * 24 + dd * 3 + mm] = a;
    }
}

// ---------------- attention logits z ----------------
__global__ void k_z(int E, const int* __restrict__ dst,
                    const float* __restrict__ kv0, const float* __restrict__ kv1,
                    const float* __restrict__ q0, const float* __restrict__ q1,
                    float* __restrict__ z) {
    int e = blockIdx.x * 256 + threadIdx.x;
    if (e >= E) return;
    int n = dst[e];
    float z0 = 0.f, z1 = 0.f, z2 = 0.f, z3 = 0.f;
#pragma unroll
    for (int d = 0; d < 8; ++d) {
        float t = q0[n * 8 + d] * kv0[e * 16 + d];
#pragma unroll
        for (int m = 0; m < 3; ++m) t += q1[(n * 8 + d) * 3 + m] * kv1[(e * 16 + d) * 3 + m];
        if (d < 2) z0 += t;
        else if (d < 4) z1 += t;
        else if (d < 6) z2 += t;
        else z3 += t;
    }
    const float scale = 0.35355339059327373f;  // 1/sqrt(8)
    z[e * 4 + 0] = z0 * scale;
    z[e * 4 + 1] = z1 * scale;
    z[e * 4 + 2] = z2 * scale;
    z[e * 4 + 3] = z3 * scale;
}

// ---------------- per-node: softmax + aggregate + proj + SE3-norm ----------------
__global__ __launch_bounds__(256) void k_attn(
    int N,
    const int* __restrict__ rowptr, const int* __restrict__ eids,
    const float* __restrict__ z, const float* __restrict__ kv0, const float* __restrict__ kv1,
    const float* __restrict__ wproj,  // (2,24,16)
    const float* __restrict__ gamma, const float* __restrict__ beta,  // (2,16)
    float* __restrict__ xs0, float* __restrict__ xs1) {
    __shared__ float wpL[768];
    __shared__ float gL[32], btL[32];
    __shared__ float inb[4][100];  // per-wave: in0[24] + in1[24*3]
    int tid = threadIdx.x;
    for (int i = tid; i < 768; i += 256) wpL[i] = wproj[i];
    if (tid < 32) { gL[tid] = gamma[tid]; btL[tid] = beta[tid]; }
    int wave = tid >> 6, lane = tid & 63;
    int n = blockIdx.x * 4 + wave;
    int base = rowptr[n], deg = rowptr[n + 1] - base;

    // segment softmax stats (per head)
    float mx0 = -INFINITY, mx1 = -INFINITY, mx2 = -INFINITY, mx3 = -INFINITY;
    for (int j = lane; j < deg; j += 64) {
        int e = eids[base + j];
        float4 zv = *(const float4*)&z[e * 4];
        mx0 = fmaxf(mx0, zv.x); mx1 = fmaxf(mx1, zv.y);
        mx2 = fmaxf(mx2, zv.z); mx3 = fmaxf(mx3, zv.w);
    }
    for (int off = 1; off < 64; off <<= 1) {
        mx0 = fmaxf(mx0, __shfl_xor(mx0, off));
        mx1 = fmaxf(mx1, __shfl_xor(mx1, off));
        mx2 = fmaxf(mx2, __shfl_xor(mx2, off));
        mx3 = fmaxf(mx3, __shfl_xor(mx3, off));
    }
    if (!isfinite(mx0)) mx0 = 0.f;
    if (!isfinite(mx1)) mx1 = 0.f;
    if (!isfinite(mx2)) mx2 = 0.f;
    if (!isfinite(mx3)) mx3 = 0.f;
    float s0 = 0.f, s1 = 0.f, s2 = 0.f, s3 = 0.f;
    for (int j = lane; j < deg; j += 64) {
        int e = eids[base + j];
        float4 zv = *(const float4*)&z[e * 4];
        s0 += __expf(zv.x - mx0); s1 += __expf(zv.y - mx1);
        s2 += __expf(zv.z - mx2); s3 += __expf(zv.w - mx3);
    }
    for (int off = 1; off < 64; off <<= 1) {
        s0 += __shfl_xor(s0, off); s1 += __shfl_xor(s1, off);
        s2 += __shfl_xor(s2, off); s3 += __shfl_xor(s3, off);
    }
    float mxa[4] = {mx0, mx1, mx2, mx3};
    float inva[4] = {1.f / (s0 + 1e-9f), 1.f / (s1 + 1e-9f),
                     1.f / (s2 + 1e-9f), 1.f / (s3 + 1e-9f)};

    // o accumulation: lanes 0..31 own the 32 attention-output components
    int kk = lane >> 3, d = lane & 7, h = d >> 1;
    float acc = 0.f;
    if (lane < 32) {
        float mh = mxa[h], ih = inva[h];
        for (int j = 0; j < deg; ++j) {
            int e = eids[base + j];
            float w = __expf(z[e * 4 + h] - mh) * ih;
            float v = (kk == 0) ? kv0[e * 16 + 8 + d] : kv1[(e * 16 + 8 + d) * 3 + (kk - 1)];
            acc += w * v;
        }
    }
    // stage concat([o, x]) into LDS
    float* in0 = &inb[wave][0];   // [24]
    float* in1 = &inb[wave][24];  // [24][3]
    if (lane < 8) in0[lane] = acc;
    else if (lane < 32) in1[d * 3 + (kk - 1)] = acc;
    if (lane < 16) in0[8 + lane] = xs0[n * 16 + lane];
    if (lane < 48) in1[24 + lane] = xs1[n * 48 + lane];
    __syncthreads();

    // projection: 64 lanes -> 64 outputs (16 for x0, 48 for x1)
    int kind = (lane < 16) ? 0 : 1;
    int c = lane & 15, mm = (lane >> 4) - 1;
    float y = 0.f;
    if (kind == 0) {
#pragma unroll
        for (int j = 0; j < 24; ++j) y += in0[j] * wpL[j * 16 + c];
    } else {
#pragma unroll
        for (int j = 0; j < 24; ++j) y += in1[j * 3 + mm] * wpL[384 + j * 16 + c];
    }
    // SE(3) norm
    float sq = (kind == 0) ? 0.f : y * y;
    sq += __shfl_xor(sq, 16);
    sq += __shfl_xor(sq, 32);
    float nrm = (kind == 0) ? sqrtf(y * y + 1e-12f) : sqrtf(sq + 1e-12f);
    float mu = nrm;
    mu += __shfl_xor(mu, 1); mu += __shfl_xor(mu, 2);
    mu += __shfl_xor(mu, 4); mu += __shfl_xor(mu, 8);
    mu *= 0.0625f;
    float dv = nrm - mu;
    float var = dv * dv;
    var += __shfl_xor(var, 1); var += __shfl_xor(var, 2);
    var += __shfl_xor(var, 4); var += __shfl_xor(var, 8);
    var *= 0.0625f;
    float ln = dv * rsqrtf(var + 1e-5f) * gL[kind * 16 + c] + btL[kind * 16 + c];
    float fac = fmaxf(ln, 0.f) / (nrm + 1e-3f);
    y *= fac;
    if (kind == 0) xs0[n * 16 + c] = y;
    else xs1[n * 48 + c * 3 + mm] = y;
}

// ---------------- final output: segment-sum(m) + x @ wself ----------------
__global__ __launch_bounds__(256) void k_out(
    int N,
    const int* __restrict__ rowptr, const int* __restrict__ eids,
    const float* __restrict__ m0f, const float* __restrict__ m1f,
    const float* __restrict__ xs0, const float* __restrict__ xs1,
    const float* __restrict__ wself,  // (2,16,8)
    float* __restrict__ out) {
    int tid = threadIdx.x;
    int wave = tid >> 6, lane = tid & 63;
    int n = blockIdx.x * 4 + wave;
    if (lane >= 32) return;
    int kk = lane >> 3, d = lane & 7;
    int base = rowptr[n], deg = rowptr[n + 1] - base;
    float acc = 0.f;
    for (int j = 0; j < deg; ++j) {
        int e = eids[base + j];
        acc += (kk == 0) ? m0f[e * 8 + d] : m1f[(e * 8 + d) * 3 + (kk - 1)];
    }
    if (kk == 0) {
#pragma unroll
        for (int c = 0; c < 16; ++c) acc += xs0[n * 16 + c] * wself[c * 8 + d];
    } else {
        int mm = kk - 1;
#pragma unroll
        for (int c = 0; c < 16; ++c) acc += xs1[n * 48 + c * 3 + mm] * wself[128 + c * 8 + d];
    }
    out[n * 32 + ((kk == 0) ? d : (8 + d * 3 + (kk - 1)))] = acc;
}

// ---------------------------------------------------------------------------
extern "C" void kernel_launch(void* const* d_in, const int* in_sizes, int n_in,
                              void* d_out, int out_size, void* d_ws, size_t ws_size,
                              hipStream_t stream) {
    const float* x0 = (const float*)d_in[0];
    const float* x1 = (const float*)d_in[1];
    const float* ef = (const float*)d_in[2];
    const float* b00 = (const float*)d_in[3];
    const float* b01 = (const float*)d_in[4];
    const float* b10 = (const float*)d_in[5];
    const float* b11 = (const float*)d_in[6];
    const float* kvw1 = (const float*)d_in[7];    // (2,4,16,16)
    const float* kvw2n = (const float*)d_in[8];   // (2,3,16,16,16)
    const float* kvw211 = (const float*)d_in[9];  // (2,16,16,16,3)
    const float* wq = (const float*)d_in[10];     // (2,2,16,8)
    const float* wproj = (const float*)d_in[11];  // (2,2,24,16)
    const float* gam = (const float*)d_in[12];    // (2,2,16)
    const float* bet = (const float*)d_in[13];
    const float* fcw1 = (const float*)d_in[14];    // (4,16,16)
    const float* fcw2n = (const float*)d_in[15];   // (3,16,8,16)
    const float* fcw211 = (const float*)d_in[16];  // (16,8,16,3)
    const float* fcself = (const float*)d_in[17];  // (2,16,8)
    const int* esrc = (const int*)d_in[18];
    const int* edst = (const int*)d_in[19];
    int N = in_sizes[0] / 16;
    int E = in_sizes[18];
    float* out = (float*)d_out;

    float* ws = (float*)d_ws;
    size_t off = 0;
    float* xs0 = ws + off; off += (size_t)N * 16;
    float* xs1 = ws + off; off += (size_t)N * 48;
    float* q0b = ws + off; off += (size_t)N * 8;
    float* q1b = ws + off; off += (size_t)N * 24;
    float* kv0 = ws + off; off += (size_t)E * 16;
    float* kv1 = ws + off; off += (size_t)E * 48;
    float* zb = ws + off; off += (size_t)E * 4;
    float* m0f = ws + off; off += (size_t)E * 8;
    float* m1f = ws + off; off += (size_t)E * 24;
    int* counts = (int*)(ws + off); off += N;
    int* rowptr = (int*)(ws + off); off += N + 1;
    int* cursor = (int*)(ws + off); off += N;
    int* eids = (int*)(ws + off); off += E;

    const int tpb = 256;
    int ebl = (E + 255) / 256;
    // CSR over edge_dst
    k_zero<<<(N + 255) / 256, tpb, 0, stream>>>(counts, N);
    k_hist<<<ebl, tpb, 0, stream>>>(edst, counts, E);
    int CH = (N + 1023) / 1024;
    k_scan<<<1, 1024, 0, stream>>>(counts, rowptr, cursor, N, CH);
    k_scatter<<<ebl, tpb, 0, stream>>>(edst, cursor, eids, E);
    k_initx<<<(N * 64 + 255) / 256, tpb, 0, stream>>>(x0, x1, xs0, xs1, N * 16, N * 48);

    for (int l = 0; l < 2; ++l) {
        k_q<<<(N * 32 + 255) / 256, tpb, 0, stream>>>(N, xs0, xs1, wq + l * 256, q0b, q1b);
        k_convA<16><<<ebl, tpb, 0, stream>>>(E, ef, b00, b01, b10, esrc, xs0, xs1,
                                             kvw1 + l * 1024, kvw2n + l * 12288, kv0, kv1);
        k_convB<16><<<ebl, tpb, 0, stream>>>(E, ef, b11, esrc, xs1,
                                             kvw1 + l * 1024 + 768, kvw211 + l * 12288, kv1);
        k_z<<<ebl, tpb, 0, stream>>>(E, edst, kv0, kv1, q0b, q1b, zb);
        k_attn<<<N / 4, tpb, 0, stream>>>(N, rowptr, eids, zb, kv0, kv1,
                                          wproj + l * 768, gam + l * 32, bet + l * 32, xs0, xs1);
    }
    k_convA<8><<<ebl, tpb, 0, stream>>>(E, ef, b00, b01, b10, esrc, xs0, xs1,
                                        fcw1, fcw2n, m0f, m1f);
    k_convB<8><<<ebl, tpb, 0, stream>>>(E, ef, b11, esrc, xs1,
                                        fcw1 + 768, fcw211, m1f);
    k_out<<<N / 4, tpb, 0, stream>>>(N, rowptr, eids, m0f, m1f, xs0, xs1, fcself, out);
}

// Round 3
// 450.204 us; speedup vs baseline: 4.5874x; 4.5874x over previous
//
#include <hip/hip_runtime.h>
#include <math.h>

// ---------------------------------------------------------------------------
// EquivariantNet forward — round 3: MFMA conv.
// out[oo] = sum_{h,i} H[h] x[i] W[h,oo,i]  ==  GEMM  C[E x KVO] = Y[E x K] W[K x KVO]
// with Y[(i,f?),h] = H[h]*x-part built in registers, K ordered h-fastest so each
// lane's 8-elem A-slice = H[h0..h0+7] * scalar. Weights pre-permuted to exact
// B-frag order (bf16) once per call. H=relu(ef@w1) precomputed per layer (bf16).
// Shapes: N=8192, E=131072, C=16, mid=16, KV=16, ckv=8, Co=8, HEADS=4, L=2
// ---------------------------------------------------------------------------

typedef short short8 __attribute__((ext_vector_type(8)));
typedef float f32x4 __attribute__((ext_vector_type(4)));
typedef float float8 __attribute__((ext_vector_type(8)));

static __device__ __forceinline__ unsigned short f2bf(float f) {
    unsigned x = __float_as_uint(f);
    unsigned r = x + 0x7FFFu + ((x >> 16) & 1u);  // RNE
    return (unsigned short)(r >> 16);
}
static __device__ __forceinline__ float bf2f(unsigned short u) {
    return __uint_as_float(((unsigned)u) << 16);
}

// ---------------- CSR build over edge_dst ----------------
__global__ void k_zero(int* p, int n) {
    int i = blockIdx.x * 256 + threadIdx.x;
    if (i < n) p[i] = 0;
}

__global__ void k_hist(const int* __restrict__ dst, int* __restrict__ counts, int E) {
    int e = blockIdx.x * 256 + threadIdx.x;
    if (e < E) atomicAdd(&counts[dst[e]], 1);
}

__global__ __launch_bounds__(1024) void k_scan(const int* __restrict__ counts,
                                               int* __restrict__ rowptr,
                                               int* __restrict__ cursor,
                                               int N, int CH) {
    __shared__ int part[1024];
    int t = threadIdx.x;
    int s = 0;
    for (int i = 0; i < CH; ++i) {
        int idx = t * CH + i;
        if (idx < N) s += counts[idx];
    }
    part[t] = s;
    __syncthreads();
    for (int off = 1; off < 1024; off <<= 1) {
        int v = (t >= off) ? part[t - off] : 0;
        __syncthreads();
        part[t] += v;
        __syncthreads();
    }
    int run = (t == 0) ? 0 : part[t - 1];
    for (int i = 0; i < CH; ++i) {
        int idx = t * CH + i;
        if (idx < N) {
            rowptr[idx] = run;
            cursor[idx] = run;
            run += counts[idx];
        }
    }
    if (t == 0) rowptr[N] = part[1023];
}

__global__ void k_scatter(const int* __restrict__ dst, int* __restrict__ cursor,
                          int* __restrict__ eids, int E) {
    int e = blockIdx.x * 256 + threadIdx.x;
    if (e < E) {
        int pos = atomicAdd(&cursor[dst[e]], 1);
        eids[pos] = e;
    }
}

// ---------------- init x working copies ----------------
__global__ void k_initx(const float* __restrict__ x0, const float* __restrict__ x1,
                        float* __restrict__ xs0, float* __restrict__ xs1, int n0, int n1) {
    int i = blockIdx.x * 256 + threadIdx.x;
    if (i < n0) xs0[i] = x0[i];
    else if (i < n0 + n1) xs1[i - n0] = x1[i - n0];
}

// ---------------- weight permute into B-fragment order (bf16) ----------------
// Wfrag[kkG][lane][j] (ushort). kkG regions: layer0: 0..47, layer1: 48..95, fc: 96..143.
// Within a region: fam0/1/2 (nf1 pp) at +0/+8/+16 (K=256, k=i*16+h);
// fam3 (1->1) at +24..+47 (K=768, k=(i*3+f)*16+h).
// Element: lane -> n=lane&15 (oo), quad=lane>>4; k = kkLocal*32 + quad*8 + j.
__global__ void k_prepw(const float* __restrict__ kvw2n, const float* __restrict__ kvw211,
                        const float* __restrict__ fcw2n, const float* __restrict__ fcw211,
                        unsigned short* __restrict__ Wfrag) {
    int t = blockIdx.x * 256 + threadIdx.x;
    if (t >= 144 * 64 * 8) return;
    int j = t & 7;
    int lane = (t >> 3) & 63;
    int kkG = t >> 9;
    int quad = lane >> 4, n = lane & 15;
    int l = kkG / 48, kkL = kkG % 48;
    int KVO = (l < 2) ? 16 : 8;
    const float* w2n = (l < 2) ? (kvw2n + l * 12288) : fcw2n;
    const float* w211 = (l < 2) ? (kvw211 + l * 12288) : fcw211;
    float v = 0.f;
    if (kkL < 24) {
        int fam = kkL >> 3;                      // 0..2
        int k = (kkL & 7) * 32 + quad * 8 + j;   // 0..255
        int i = k >> 4, h = k & 15;
        if (n < KVO) v = w2n[((fam * 16 + h) * KVO + n) * 16 + i];
    } else {
        int k = (kkL - 24) * 32 + quad * 8 + j;  // 0..767
        int if_ = k >> 4, h = k & 15;
        int i = if_ / 3, f = if_ % 3;
        if (n < KVO) v = w211[((h * KVO + n) * 16 + i) * 3 + f];
    }
    Wfrag[t] = f2bf(v);
}

// ---------------- H = relu(ef @ w1) per conv, bf16 ----------------
// Hb layout: [pp(4)][e][16h]
__global__ void k_H(int E, const float* __restrict__ ef, const float* __restrict__ w1,
                    unsigned short* __restrict__ Hb) {
    int t = blockIdx.x * 256 + threadIdx.x;
    if (t >= 4 * E) return;
    int pp = t / E, e = t % E;
    float efr[16];
    const float4* p = (const float4*)(ef + (size_t)e * 16);
#pragma unroll
    for (int k = 0; k < 4; ++k) {
        float4 v = p[k];
        efr[k * 4 + 0] = v.x; efr[k * 4 + 1] = v.y;
        efr[k * 4 + 2] = v.z; efr[k * 4 + 3] = v.w;
    }
    float H[16];
#pragma unroll
    for (int h = 0; h < 16; ++h) H[h] = 0.f;
#pragma unroll
    for (int f = 0; f < 16; ++f) {
        const float* wr = w1 + (pp * 16 + f) * 16;
#pragma unroll
        for (int h = 0; h < 16; ++h) H[h] += efr[f] * wr[h];
    }
    unsigned out[8];
#pragma unroll
    for (int k = 0; k < 8; ++k) {
        unsigned lo = f2bf(fmaxf(H[2 * k], 0.f));
        unsigned hi = f2bf(fmaxf(H[2 * k + 1], 0.f));
        out[k] = lo | (hi << 16);
    }
    uint4* dst = (uint4*)(Hb + (size_t)t * 16);
    dst[0] = make_uint4(out[0], out[1], out[2], out[3]);
    dst[1] = make_uint4(out[4], out[5], out[6], out[7]);
}

// ---------------- fused MFMA conv: all 4 pair families ----------------
// One wave per 16-edge tile. Writes out0 (E,KVO) and out1 (E,KVO,3) fully.
template <int KVO>
__global__ __launch_bounds__(256) void k_conv(
    int E,
    const int* __restrict__ src,
    const float* __restrict__ xs0, const float* __restrict__ xs1,
    const float* __restrict__ b00, const float* __restrict__ b01,
    const float* __restrict__ b10, const float* __restrict__ b11,
    const unsigned short* __restrict__ Hb,     // [4][E][16] bf16
    const unsigned short* __restrict__ Wfrag,  // frag-ordered weights
    int fb0,                                   // kk base for this conv
    float* __restrict__ out0, float* __restrict__ out1)
{
    __shared__ float xBL[4][16 * 148];  // per-wave: [m][p*48 + if], stride 148
    int tid = threadIdx.x;
    int wave = tid >> 6, lane = tid & 63;
    int tile = blockIdx.x * 4 + wave;
    if (tile * 16 >= E) return;
    int m = lane & 15, quad = lane >> 4;
    int h0 = (quad & 1) * 8;
    int qh = quad >> 1;
    int e0 = tile * 16;
    int me = e0 + m;
    int s = src[me];
    float* xw = xBL[wave];

    // ---- per-lane x0 / t10 selections (i = 2*kk + qh) ----
    float x0s[8], t10s[8];
    float bq0 = b10[(size_t)me * 3 + 0], bq1 = b10[(size_t)me * 3 + 1], bq2 = b10[(size_t)me * 3 + 2];
#pragma unroll
    for (int kk = 0; kk < 8; ++kk) {
        int i = 2 * kk + qh;
        x0s[kk] = xs0[(size_t)s * 16 + i];
        const float* xp = xs1 + (size_t)s * 48 + i * 3;
        t10s[kk] = bq0 * xp[0] + bq1 * xp[1] + bq2 * xp[2];
    }

    // ---- xB[p][if] = sum_q x1[i][q]*b11[p][q][f], this lane covers if in [quad*12, quad*12+12) ----
    {
        float x1c[12];
        const float4* xp = (const float4*)(xs1 + (size_t)s * 48 + quad * 12);
#pragma unroll
        for (int c = 0; c < 3; ++c) {
            float4 v = xp[c];
            x1c[c * 4 + 0] = v.x; x1c[c * 4 + 1] = v.y;
            x1c[c * 4 + 2] = v.z; x1c[c * 4 + 3] = v.w;
        }
        float b11r[27];
#pragma unroll
        for (int k = 0; k < 27; ++k) b11r[k] = b11[(size_t)me * 27 + k];
#pragma unroll
        for (int p = 0; p < 3; ++p) {
            float vals[12];
#pragma unroll
            for (int i2 = 0; i2 < 4; ++i2) {
#pragma unroll
                for (int f = 0; f < 3; ++f) {
                    float a = 0.f;
#pragma unroll
                    for (int q = 0; q < 3; ++q) a += x1c[i2 * 3 + q] * b11r[p * 9 + q * 3 + f];
                    vals[i2 * 3 + f] = a;
                }
            }
#pragma unroll
            for (int c = 0; c < 3; ++c) {
                float4 v = make_float4(vals[c * 4 + 0], vals[c * 4 + 1], vals[c * 4 + 2], vals[c * 4 + 3]);
                *(float4*)&xw[m * 148 + p * 48 + quad * 12 + c * 4] = v;
            }
        }
    }

    // ---- H slices (registers): H[pp][h0 + j], j=0..7 ----
    float8 H0v, H1v, H2v, H3v;
    {
        const short8* hp0 = (const short8*)(Hb + ((size_t)(0 * E + me) * 16 + h0));
        const short8* hp1 = (const short8*)(Hb + ((size_t)(1 * E + me) * 16 + h0));
        const short8* hp2 = (const short8*)(Hb + ((size_t)(2 * E + me) * 16 + h0));
        const short8* hp3 = (const short8*)(Hb + ((size_t)(3 * E + me) * 16 + h0));
        short8 a = *hp0, b = *hp1, c = *hp2, d = *hp3;
#pragma unroll
        for (int j = 0; j < 8; ++j) {
            H0v[j] = bf2f((unsigned short)a[j]);
            H1v[j] = bf2f((unsigned short)b[j]);
            H2v[j] = bf2f((unsigned short)c[j]);
            H3v[j] = bf2f((unsigned short)d[j]);
        }
    }

    const short8* W8 = (const short8*)Wfrag;
    f32x4 acc0 = {0.f, 0.f, 0.f, 0.f}, acc1 = acc0, acc2 = acc0;
    f32x4 accP0 = acc0, accP1 = acc0, accP2 = acc0;

    // ---- loop1: fams 0,1,2 (K=256) ----
#pragma unroll
    for (int kk = 0; kk < 8; ++kk) {
        float xv = x0s[kk], tv = t10s[kk];
        short8 a0, a1, a2;
#pragma unroll
        for (int j = 0; j < 8; ++j) {
            a0[j] = (short)f2bf(H0v[j] * xv);
            a1[j] = (short)f2bf(H1v[j] * xv);
            a2[j] = (short)f2bf(H2v[j] * tv);
        }
        short8 b0 = W8[(size_t)(fb0 + kk) * 64 + lane];
        short8 b1 = W8[(size_t)(fb0 + 8 + kk) * 64 + lane];
        short8 b2 = W8[(size_t)(fb0 + 16 + kk) * 64 + lane];
        acc0 = __builtin_amdgcn_mfma_f32_16x16x32_bf16(a0, b0, acc0, 0, 0, 0);
        acc1 = __builtin_amdgcn_mfma_f32_16x16x32_bf16(a1, b1, acc1, 0, 0, 0);
        acc2 = __builtin_amdgcn_mfma_f32_16x16x32_bf16(a2, b2, acc2, 0, 0, 0);
    }

    // ---- loop2: fam3 (K=768), 3 p-GEMMs share B ----
#pragma unroll
    for (int kk = 0; kk < 24; ++kk) {
        int if_ = 2 * kk + qh;
        float xb0 = xw[m * 148 + 0 * 48 + if_];
        float xb1 = xw[m * 148 + 1 * 48 + if_];
        float xb2 = xw[m * 148 + 2 * 48 + if_];
        short8 a0, a1, a2;
#pragma unroll
        for (int j = 0; j < 8; ++j) {
            a0[j] = (short)f2bf(H3v[j] * xb0);
            a1[j] = (short)f2bf(H3v[j] * xb1);
            a2[j] = (short)f2bf(H3v[j] * xb2);
        }
        short8 b3 = W8[(size_t)(fb0 + 24 + kk) * 64 + lane];
        accP0 = __builtin_amdgcn_mfma_f32_16x16x32_bf16(a0, b3, accP0, 0, 0, 0);
        accP1 = __builtin_amdgcn_mfma_f32_16x16x32_bf16(a1, b3, accP1, 0, 0, 0);
        accP2 = __builtin_amdgcn_mfma_f32_16x16x32_bf16(a2, b3, accP2, 0, 0, 0);
    }

    // ---- epilogue: rows r -> edge e0 + quad*4 + r; col = oo = m ----
    int oo = m;
    if (oo < KVO) {
        float4 b00v = *(const float4*)(b00 + e0 + quad * 4);
        const float4* b01p = (const float4*)(b01 + (size_t)(e0 + quad * 4) * 3);
        float4 bA = b01p[0], bB = b01p[1], bC = b01p[2];
        float b01v[12] = {bA.x, bA.y, bA.z, bA.w, bB.x, bB.y, bB.z, bB.w, bC.x, bC.y, bC.z, bC.w};
        float b00a[4] = {b00v.x, b00v.y, b00v.z, b00v.w};
#pragma unroll
        for (int r = 0; r < 4; ++r) {
            int er = e0 + quad * 4 + r;
            out0[(size_t)er * KVO + oo] = b00a[r] * acc0[r] + acc2[r];
            size_t base = ((size_t)er * KVO + oo) * 3;
            out1[base + 0] = b01v[r * 3 + 0] * acc1[r] + accP0[r];
            out1[base + 1] = b01v[r * 3 + 1] * acc1[r] + accP1[r];
            out1[base + 2] = b01v[r * 3 + 2] * acc1[r] + accP2[r];
        }
    }
}

// ---------------- q projection ----------------
__global__ void k_q(int N, const float* __restrict__ xs0, const float* __restrict__ xs1,
                    const float* __restrict__ wq,  // (2,16,8) for this layer
                    float* __restrict__ q0, float* __restrict__ q1) {
    int t = blockIdx.x * 256 + threadIdx.x;
    if (t >= N * 32) return;
    int n = t >> 5, comp = t & 31;
    if (comp < 8) {
        float a = 0.f;
#pragma unroll
        for (int c = 0; c < 16; ++c) a += xs0[n * 16 + c] * wq[c * 8 + comp];
        q0[n * 8 + comp] = a;
    } else {
        int idx = comp - 8, dd = idx / 3, mm = idx % 3;
        float a = 0.f;
#pragma unroll
        for (int c = 0; c < 16; ++c) a += xs1[n * 48 + c * 3 + mm] * wq[128 + c * 8 + dd];
        q1[n * 24 + dd * 3 + mm] = a;
    }
}

// ---------------- attention logits z ----------------
__global__ void k_z(int E, const int* __restrict__ dst,
                    const float* __restrict__ kv0, const float* __restrict__ kv1,
                    const float* __restrict__ q0, const float* __restrict__ q1,
                    float* __restrict__ z) {
    int e = blockIdx.x * 256 + threadIdx.x;
    if (e >= E) return;
    int n = dst[e];
    float z0 = 0.f, z1 = 0.f, z2 = 0.f, z3 = 0.f;
#pragma unroll
    for (int d = 0; d < 8; ++d) {
        float t = q0[n * 8 + d] * kv0[e * 16 + d];
#pragma unroll
        for (int m = 0; m < 3; ++m) t += q1[(n * 8 + d) * 3 + m] * kv1[(e * 16 + d) * 3 + m];
        if (d < 2) z0 += t;
        else if (d < 4) z1 += t;
        else if (d < 6) z2 += t;
        else z3 += t;
    }
    const float scale = 0.35355339059327373f;  // 1/sqrt(8)
    z[e * 4 + 0] = z0 * scale;
    z[e * 4 + 1] = z1 * scale;
    z[e * 4 + 2] = z2 * scale;
    z[e * 4 + 3] = z3 * scale;
}

// ---------------- per-node: softmax + aggregate + proj + SE3-norm ----------------
__global__ __launch_bounds__(256) void k_attn(
    int N,
    const int* __restrict__ rowptr, const int* __restrict__ eids,
    const float* __restrict__ z, const float* __restrict__ kv0, const float* __restrict__ kv1,
    const float* __restrict__ wproj,  // (2,24,16)
    const float* __restrict__ gamma, const float* __restrict__ beta,  // (2,16)
    float* __restrict__ xs0, float* __restrict__ xs1) {
    __shared__ float wpL[768];
    __shared__ float gL[32], btL[32];
    __shared__ float inb[4][100];  // per-wave: in0[24] + in1[24*3]
    int tid = threadIdx.x;
    for (int i = tid; i < 768; i += 256) wpL[i] = wproj[i];
    if (tid < 32) { gL[tid] = gamma[tid]; btL[tid] = beta[tid]; }
    int wave = tid >> 6, lane = tid & 63;
    int n = blockIdx.x * 4 + wave;
    int base = rowptr[n], deg = rowptr[n + 1] - base;

    float mx0 = -INFINITY, mx1 = -INFINITY, mx2 = -INFINITY, mx3 = -INFINITY;
    for (int j = lane; j < deg; j += 64) {
        int e = eids[base + j];
        float4 zv = *(const float4*)&z[e * 4];
        mx0 = fmaxf(mx0, zv.x); mx1 = fmaxf(mx1, zv.y);
        mx2 = fmaxf(mx2, zv.z); mx3 = fmaxf(mx3, zv.w);
    }
    for (int off = 1; off < 64; off <<= 1) {
        mx0 = fmaxf(mx0, __shfl_xor(mx0, off));
        mx1 = fmaxf(mx1, __shfl_xor(mx1, off));
        mx2 = fmaxf(mx2, __shfl_xor(mx2, off));
        mx3 = fmaxf(mx3, __shfl_xor(mx3, off));
    }
    if (!isfinite(mx0)) mx0 = 0.f;
    if (!isfinite(mx1)) mx1 = 0.f;
    if (!isfinite(mx2)) mx2 = 0.f;
    if (!isfinite(mx3)) mx3 = 0.f;
    float s0 = 0.f, s1 = 0.f, s2 = 0.f, s3 = 0.f;
    for (int j = lane; j < deg; j += 64) {
        int e = eids[base + j];
        float4 zv = *(const float4*)&z[e * 4];
        s0 += __expf(zv.x - mx0); s1 += __expf(zv.y - mx1);
        s2 += __expf(zv.z - mx2); s3 += __expf(zv.w - mx3);
    }
    for (int off = 1; off < 64; off <<= 1) {
        s0 += __shfl_xor(s0, off); s1 += __shfl_xor(s1, off);
        s2 += __shfl_xor(s2, off); s3 += __shfl_xor(s3, off);
    }
    float mxa[4] = {mx0, mx1, mx2, mx3};
    float inva[4] = {1.f / (s0 + 1e-9f), 1.f / (s1 + 1e-9f),
                     1.f / (s2 + 1e-9f), 1.f / (s3 + 1e-9f)};

    int kk = lane >> 3, d = lane & 7, h = d >> 1;
    float acc = 0.f;
    if (lane < 32) {
        float mh = mxa[h], ih = inva[h];
        for (int j = 0; j < deg; ++j) {
            int e = eids[base + j];
            float w = __expf(z[e * 4 + h] - mh) * ih;
            float v = (kk == 0) ? kv0[e * 16 + 8 + d] : kv1[(e * 16 + 8 + d) * 3 + (kk - 1)];
            acc += w * v;
        }
    }
    float* in0 = &inb[wave][0];   // [24]
    float* in1 = &inb[wave][24];  // [24][3]
    if (lane < 8) in0[lane] = acc;
    else if (lane < 32) in1[d * 3 + (kk - 1)] = acc;
    if (lane < 16) in0[8 + lane] = xs0[n * 16 + lane];
    if (lane < 48) in1[24 + lane] = xs1[n * 48 + lane];
    __syncthreads();

    int kind = (lane < 16) ? 0 : 1;
    int c = lane & 15, mm = (lane >> 4) - 1;
    float y = 0.f;
    if (kind == 0) {
#pragma unroll
        for (int j = 0; j < 24; ++j) y += in0[j] * wpL[j * 16 + c];
    } else {
#pragma unroll
        for (int j = 0; j < 24; ++j) y += in1[j * 3 + mm] * wpL[384 + j * 16 + c];
    }
    float sq = (kind == 0) ? 0.f : y * y;
    sq += __shfl_xor(sq, 16);
    sq += __shfl_xor(sq, 32);
    float nrm = (kind == 0) ? sqrtf(y * y + 1e-12f) : sqrtf(sq + 1e-12f);
    float mu = nrm;
    mu += __shfl_xor(mu, 1); mu += __shfl_xor(mu, 2);
    mu += __shfl_xor(mu, 4); mu += __shfl_xor(mu, 8);
    mu *= 0.0625f;
    float dv = nrm - mu;
    float var = dv * dv;
    var += __shfl_xor(var, 1); var += __shfl_xor(var, 2);
    var += __shfl_xor(var, 4); var += __shfl_xor(var, 8);
    var *= 0.0625f;
    float ln = dv * rsqrtf(var + 1e-5f) * gL[kind * 16 + c] + btL[kind * 16 + c];
    float fac = fmaxf(ln, 0.f) / (nrm + 1e-3f);
    y *= fac;
    if (kind == 0) xs0[n * 16 + c] = y;
    else xs1[n * 48 + c * 3 + mm] = y;
}

// ---------------- final output: segment-sum(m) + x @ wself ----------------
__global__ __launch_bounds__(256) void k_out(
    int N,
    const int* __restrict__ rowptr, const int* __restrict__ eids,
    const float* __restrict__ m0f, const float* __restrict__ m1f,
    const float* __restrict__ xs0, const float* __restrict__ xs1,
    const float* __restrict__ wself,  // (2,16,8)
    float* __restrict__ out) {
    int tid = threadIdx.x;
    int wave = tid >> 6, lane = tid & 63;
    int n = blockIdx.x * 4 + wave;
    if (lane >= 32) return;
    int kk = lane >> 3, d = lane & 7;
    int base = rowptr[n], deg = rowptr[n + 1] - base;
    float acc = 0.f;
    for (int j = 0; j < deg; ++j) {
        int e = eids[base + j];
        acc += (kk == 0) ? m0f[e * 8 + d] : m1f[(e * 8 + d) * 3 + (kk - 1)];
    }
    if (kk == 0) {
#pragma unroll
        for (int c = 0; c < 16; ++c) acc += xs0[n * 16 + c] * wself[c * 8 + d];
    } else {
        int mm = kk - 1;
#pragma unroll
        for (int c = 0; c < 16; ++c) acc += xs1[n * 48 + c * 3 + mm] * wself[128 + c * 8 + d];
    }
    out[n * 32 + ((kk == 0) ? d : (8 + d * 3 + (kk - 1)))] = acc;
}

// ---------------------------------------------------------------------------
extern "C" void kernel_launch(void* const* d_in, const int* in_sizes, int n_in,
                              void* d_out, int out_size, void* d_ws, size_t ws_size,
                              hipStream_t stream) {
    const float* x0 = (const float*)d_in[0];
    const float* x1 = (const float*)d_in[1];
    const float* ef = (const float*)d_in[2];
    const float* b00 = (const float*)d_in[3];
    const float* b01 = (const float*)d_in[4];
    const float* b10 = (const float*)d_in[5];
    const float* b11 = (const float*)d_in[6];
    const float* kvw1 = (const float*)d_in[7];    // (2,4,16,16)
    const float* kvw2n = (const float*)d_in[8];   // (2,3,16,16,16)
    const float* kvw211 = (const float*)d_in[9];  // (2,16,16,16,3)
    const float* wq = (const float*)d_in[10];     // (2,2,16,8)
    const float* wproj = (const float*)d_in[11];  // (2,2,24,16)
    const float* gam = (const float*)d_in[12];    // (2,2,16)
    const float* bet = (const float*)d_in[13];
    const float* fcw1 = (const float*)d_in[14];    // (4,16,16)
    const float* fcw2n = (const float*)d_in[15];   // (3,16,8,16)
    const float* fcw211 = (const float*)d_in[16];  // (16,8,16,3)
    const float* fcself = (const float*)d_in[17];  // (2,16,8)
    const int* esrc = (const int*)d_in[18];
    const int* edst = (const int*)d_in[19];
    int N = in_sizes[0] / 16;
    int E = in_sizes[18];
    float* out = (float*)d_out;

    float* ws = (float*)d_ws;
    size_t off = 0;
    float* xs0 = ws + off; off += (size_t)N * 16;
    float* xs1 = ws + off; off += (size_t)N * 48;
    float* q0b = ws + off; off += (size_t)N * 8;
    float* q1b = ws + off; off += (size_t)N * 24;
    float* kv0 = ws + off; off += (size_t)E * 16;   // also fc m0 (E,8)
    float* kv1 = ws + off; off += (size_t)E * 48;   // also fc m1 (E,8,3)
    float* zb = ws + off; off += (size_t)E * 4;
    int* counts = (int*)(ws + off); off += N;
    int* rowptr = (int*)(ws + off); off += N + 1;
    int* cursor = (int*)(ws + off); off += N;
    int* eids = (int*)(ws + off); off += E;
    off = (off + 3) & ~(size_t)3;
    unsigned short* Hbuf = (unsigned short*)(ws + off); off += (size_t)4 * E * 16 / 2;   // bf16
    unsigned short* Wfrag = (unsigned short*)(ws + off); off += (size_t)144 * 64 * 8 / 2;

    const int tpb = 256;
    int ebl = (E + 255) / 256;
    int cblk = (E / 16 + 3) / 4;  // tiles/4 waves

    k_prepw<<<288, tpb, 0, stream>>>(kvw2n, kvw211, fcw2n, fcw211, Wfrag);
    // CSR over edge_dst
    k_zero<<<(N + 255) / 256, tpb, 0, stream>>>(counts, N);
    k_hist<<<ebl, tpb, 0, stream>>>(edst, counts, E);
    int CH = (N + 1023) / 1024;
    k_scan<<<1, 1024, 0, stream>>>(counts, rowptr, cursor, N, CH);
    k_scatter<<<ebl, tpb, 0, stream>>>(edst, cursor, eids, E);
    k_initx<<<(N * 64 + 255) / 256, tpb, 0, stream>>>(x0, x1, xs0, xs1, N * 16, N * 48);

    for (int l = 0; l < 2; ++l) {
        k_H<<<(4 * E + 255) / 256, tpb, 0, stream>>>(E, ef, kvw1 + l * 1024, Hbuf);
        k_q<<<(N * 32 + 255) / 256, tpb, 0, stream>>>(N, xs0, xs1, wq + l * 256, q0b, q1b);
        k_conv<16><<<cblk, tpb, 0, stream>>>(E, esrc, xs0, xs1, b00, b01, b10, b11,
                                             Hbuf, Wfrag, l * 48, kv0, kv1);
        k_z<<<ebl, tpb, 0, stream>>>(E, edst, kv0, kv1, q0b, q1b, zb);
        k_attn<<<N / 4, tpb, 0, stream>>>(N, rowptr, eids, zb, kv0, kv1,
                                          wproj + l * 768, gam + l * 32, bet + l * 32, xs0, xs1);
    }
    k_H<<<(4 * E + 255) / 256, tpb, 0, stream>>>(E, ef, fcw1, Hbuf);
    k_conv<8><<<cblk, tpb, 0, stream>>>(E, esrc, xs0, xs1, b00, b01, b10, b11,
                                        Hbuf, Wfrag, 96, kv0, kv1);
    k_out<<<N / 4, tpb, 0, stream>>>(N, rowptr, eids, kv0, kv1, xs0, xs1, fcself, out);
}

// Round 4
// 414.896 us; speedup vs baseline: 4.9778x; 1.0851x over previous
//
#include <hip/hip_runtime.h>
#include <hip/hip_bf16.h>
#include <math.h>

// ---------------------------------------------------------------------------
// EquivariantNet forward — round 4.
// r3 structure + (1) packed bf16 cvt in MFMA A-build (v_cvt_pk_bf16_f32),
// (2) k_attn/k_out restructured to 4 nodes/wave (16 lanes per node).
// Shapes: N=8192, E=131072, C=16, mid=16, KV=16, ckv=8, Co=8, HEADS=4, L=2
// ---------------------------------------------------------------------------

typedef short short8 __attribute__((ext_vector_type(8)));
typedef float f32x4 __attribute__((ext_vector_type(4)));
typedef float float8 __attribute__((ext_vector_type(8)));

union ABfrag {
    short8 s8;
    __hip_bfloat162 b2[4];
};

static __device__ __forceinline__ unsigned short f2bf(float f) {
    unsigned x = __float_as_uint(f);
    unsigned r = x + 0x7FFFu + ((x >> 16) & 1u);  // RNE
    return (unsigned short)(r >> 16);
}
static __device__ __forceinline__ float bf2f(unsigned short u) {
    return __uint_as_float(((unsigned)u) << 16);
}

// ---------------- CSR build over edge_dst ----------------
__global__ void k_zero(int* p, int n) {
    int i = blockIdx.x * 256 + threadIdx.x;
    if (i < n) p[i] = 0;
}

__global__ void k_hist(const int* __restrict__ dst, int* __restrict__ counts, int E) {
    int e = blockIdx.x * 256 + threadIdx.x;
    if (e < E) atomicAdd(&counts[dst[e]], 1);
}

__global__ __launch_bounds__(1024) void k_scan(const int* __restrict__ counts,
                                               int* __restrict__ rowptr,
                                               int* __restrict__ cursor,
                                               int N, int CH) {
    __shared__ int part[1024];
    int t = threadIdx.x;
    int s = 0;
    for (int i = 0; i < CH; ++i) {
        int idx = t * CH + i;
        if (idx < N) s += counts[idx];
    }
    part[t] = s;
    __syncthreads();
    for (int off = 1; off < 1024; off <<= 1) {
        int v = (t >= off) ? part[t - off] : 0;
        __syncthreads();
        part[t] += v;
        __syncthreads();
    }
    int run = (t == 0) ? 0 : part[t - 1];
    for (int i = 0; i < CH; ++i) {
        int idx = t * CH + i;
        if (idx < N) {
            rowptr[idx] = run;
            cursor[idx] = run;
            run += counts[idx];
        }
    }
    if (t == 0) rowptr[N] = part[1023];
}

__global__ void k_scatter(const int* __restrict__ dst, int* __restrict__ cursor,
                          int* __restrict__ eids, int E) {
    int e = blockIdx.x * 256 + threadIdx.x;
    if (e < E) {
        int pos = atomicAdd(&cursor[dst[e]], 1);
        eids[pos] = e;
    }
}

// ---------------- init x working copies ----------------
__global__ void k_initx(const float* __restrict__ x0, const float* __restrict__ x1,
                        float* __restrict__ xs0, float* __restrict__ xs1, int n0, int n1) {
    int i = blockIdx.x * 256 + threadIdx.x;
    if (i < n0) xs0[i] = x0[i];
    else if (i < n0 + n1) xs1[i - n0] = x1[i - n0];
}

// ---------------- weight permute into B-fragment order (bf16) ----------------
__global__ void k_prepw(const float* __restrict__ kvw2n, const float* __restrict__ kvw211,
                        const float* __restrict__ fcw2n, const float* __restrict__ fcw211,
                        unsigned short* __restrict__ Wfrag) {
    int t = blockIdx.x * 256 + threadIdx.x;
    if (t >= 144 * 64 * 8) return;
    int j = t & 7;
    int lane = (t >> 3) & 63;
    int kkG = t >> 9;
    int quad = lane >> 4, n = lane & 15;
    int l = kkG / 48, kkL = kkG % 48;
    int KVO = (l < 2) ? 16 : 8;
    const float* w2n = (l < 2) ? (kvw2n + l * 12288) : fcw2n;
    const float* w211 = (l < 2) ? (kvw211 + l * 12288) : fcw211;
    float v = 0.f;
    if (kkL < 24) {
        int fam = kkL >> 3;                      // 0..2
        int k = (kkL & 7) * 32 + quad * 8 + j;   // 0..255
        int i = k >> 4, h = k & 15;
        if (n < KVO) v = w2n[((fam * 16 + h) * KVO + n) * 16 + i];
    } else {
        int k = (kkL - 24) * 32 + quad * 8 + j;  // 0..767
        int if_ = k >> 4, h = k & 15;
        int i = if_ / 3, f = if_ % 3;
        if (n < KVO) v = w211[((h * KVO + n) * 16 + i) * 3 + f];
    }
    Wfrag[t] = f2bf(v);
}

// ---------------- H = relu(ef @ w1) per conv, bf16 ----------------
// Hb layout: [pp(4)][e][16h]
__global__ void k_H(int E, const float* __restrict__ ef, const float* __restrict__ w1,
                    unsigned short* __restrict__ Hb) {
    int t = blockIdx.x * 256 + threadIdx.x;
    if (t >= 4 * E) return;
    int pp = t / E, e = t % E;
    float efr[16];
    const float4* p = (const float4*)(ef + (size_t)e * 16);
#pragma unroll
    for (int k = 0; k < 4; ++k) {
        float4 v = p[k];
        efr[k * 4 + 0] = v.x; efr[k * 4 + 1] = v.y;
        efr[k * 4 + 2] = v.z; efr[k * 4 + 3] = v.w;
    }
    float H[16];
#pragma unroll
    for (int h = 0; h < 16; ++h) H[h] = 0.f;
#pragma unroll
    for (int f = 0; f < 16; ++f) {
        const float* wr = w1 + (pp * 16 + f) * 16;
#pragma unroll
        for (int h = 0; h < 16; ++h) H[h] += efr[f] * wr[h];
    }
    unsigned out[8];
#pragma unroll
    for (int k = 0; k < 8; ++k) {
        unsigned lo = f2bf(fmaxf(H[2 * k], 0.f));
        unsigned hi = f2bf(fmaxf(H[2 * k + 1], 0.f));
        out[k] = lo | (hi << 16);
    }
    uint4* dst = (uint4*)(Hb + (size_t)t * 16);
    dst[0] = make_uint4(out[0], out[1], out[2], out[3]);
    dst[1] = make_uint4(out[4], out[5], out[6], out[7]);
}

// ---------------- fused MFMA conv: all 4 pair families ----------------
template <int KVO>
__global__ __launch_bounds__(256) void k_conv(
    int E,
    const int* __restrict__ src,
    const float* __restrict__ xs0, const float* __restrict__ xs1,
    const float* __restrict__ b00, const float* __restrict__ b01,
    const float* __restrict__ b10, const float* __restrict__ b11,
    const unsigned short* __restrict__ Hb,     // [4][E][16] bf16
    const unsigned short* __restrict__ Wfrag,  // frag-ordered weights
    int fb0,
    float* __restrict__ out0, float* __restrict__ out1)
{
    __shared__ float xBL[4][16 * 148];  // per-wave: [m][p*48 + if], stride 148
    int tid = threadIdx.x;
    int wave = tid >> 6, lane = tid & 63;
    int tile = blockIdx.x * 4 + wave;
    if (tile * 16 >= E) return;
    int m = lane & 15, quad = lane >> 4;
    int h0 = (quad & 1) * 8;
    int qh = quad >> 1;
    int e0 = tile * 16;
    int me = e0 + m;
    int s = src[me];
    float* xw = xBL[wave];

    // ---- per-lane x0 / t10 selections (i = 2*kk + qh) ----
    float x0s[8], t10s[8];
    float bq0 = b10[(size_t)me * 3 + 0], bq1 = b10[(size_t)me * 3 + 1], bq2 = b10[(size_t)me * 3 + 2];
#pragma unroll
    for (int kk = 0; kk < 8; ++kk) {
        int i = 2 * kk + qh;
        x0s[kk] = xs0[(size_t)s * 16 + i];
        const float* xp = xs1 + (size_t)s * 48 + i * 3;
        t10s[kk] = bq0 * xp[0] + bq1 * xp[1] + bq2 * xp[2];
    }

    // ---- xB[p][if] = sum_q x1[i][q]*b11[p][q][f] ----
    {
        float x1c[12];
        const float4* xp = (const float4*)(xs1 + (size_t)s * 48 + quad * 12);
#pragma unroll
        for (int c = 0; c < 3; ++c) {
            float4 v = xp[c];
            x1c[c * 4 + 0] = v.x; x1c[c * 4 + 1] = v.y;
            x1c[c * 4 + 2] = v.z; x1c[c * 4 + 3] = v.w;
        }
        float b11r[27];
#pragma unroll
        for (int k = 0; k < 27; ++k) b11r[k] = b11[(size_t)me * 27 + k];
#pragma unroll
        for (int p = 0; p < 3; ++p) {
            float vals[12];
#pragma unroll
            for (int i2 = 0; i2 < 4; ++i2) {
#pragma unroll
                for (int f = 0; f < 3; ++f) {
                    float a = 0.f;
#pragma unroll
                    for (int q = 0; q < 3; ++q) a += x1c[i2 * 3 + q] * b11r[p * 9 + q * 3 + f];
                    vals[i2 * 3 + f] = a;
                }
            }
#pragma unroll
            for (int c = 0; c < 3; ++c) {
                float4 v = make_float4(vals[c * 4 + 0], vals[c * 4 + 1], vals[c * 4 + 2], vals[c * 4 + 3]);
                *(float4*)&xw[m * 148 + p * 48 + quad * 12 + c * 4] = v;
            }
        }
    }

    // ---- H slices (registers): H[pp][h0 + j], j=0..7 ----
    float8 H0v, H1v, H2v, H3v;
    {
        const short8* hp0 = (const short8*)(Hb + ((size_t)(0 * E + me) * 16 + h0));
        const short8* hp1 = (const short8*)(Hb + ((size_t)(1 * E + me) * 16 + h0));
        const short8* hp2 = (const short8*)(Hb + ((size_t)(2 * E + me) * 16 + h0));
        const short8* hp3 = (const short8*)(Hb + ((size_t)(3 * E + me) * 16 + h0));
        short8 a = *hp0, b = *hp1, c = *hp2, d = *hp3;
#pragma unroll
        for (int j = 0; j < 8; ++j) {
            H0v[j] = bf2f((unsigned short)a[j]);
            H1v[j] = bf2f((unsigned short)b[j]);
            H2v[j] = bf2f((unsigned short)c[j]);
            H3v[j] = bf2f((unsigned short)d[j]);
        }
    }

    const short8* W8 = (const short8*)Wfrag;
    f32x4 acc0 = {0.f, 0.f, 0.f, 0.f}, acc1 = acc0, acc2 = acc0;
    f32x4 accP0 = acc0, accP1 = acc0, accP2 = acc0;

    // ---- loop1: fams 0,1,2 (K=256) ----
#pragma unroll
    for (int kk = 0; kk < 8; ++kk) {
        float xv = x0s[kk], tv = t10s[kk];
        ABfrag a0, a1, a2;
#pragma unroll
        for (int j2 = 0; j2 < 4; ++j2) {
            a0.b2[j2] = __float22bfloat162_rn(make_float2(H0v[2 * j2] * xv, H0v[2 * j2 + 1] * xv));
            a1.b2[j2] = __float22bfloat162_rn(make_float2(H1v[2 * j2] * xv, H1v[2 * j2 + 1] * xv));
            a2.b2[j2] = __float22bfloat162_rn(make_float2(H2v[2 * j2] * tv, H2v[2 * j2 + 1] * tv));
        }
        short8 b0 = W8[(size_t)(fb0 + kk) * 64 + lane];
        short8 b1 = W8[(size_t)(fb0 + 8 + kk) * 64 + lane];
        short8 b2 = W8[(size_t)(fb0 + 16 + kk) * 64 + lane];
        acc0 = __builtin_amdgcn_mfma_f32_16x16x32_bf16(a0.s8, b0, acc0, 0, 0, 0);
        acc1 = __builtin_amdgcn_mfma_f32_16x16x32_bf16(a1.s8, b1, acc1, 0, 0, 0);
        acc2 = __builtin_amdgcn_mfma_f32_16x16x32_bf16(a2.s8, b2, acc2, 0, 0, 0);
    }

    // ---- loop2: fam3 (K=768), 3 p-GEMMs share B ----
#pragma unroll
    for (int kk = 0; kk < 24; ++kk) {
        int if_ = 2 * kk + qh;
        float xb0 = xw[m * 148 + 0 * 48 + if_];
        float xb1 = xw[m * 148 + 1 * 48 + if_];
        float xb2 = xw[m * 148 + 2 * 48 + if_];
        ABfrag a0, a1, a2;
#pragma unroll
        for (int j2 = 0; j2 < 4; ++j2) {
            float hlo = H3v[2 * j2], hhi = H3v[2 * j2 + 1];
            a0.b2[j2] = __float22bfloat162_rn(make_float2(hlo * xb0, hhi * xb0));
            a1.b2[j2] = __float22bfloat162_rn(make_float2(hlo * xb1, hhi * xb1));
            a2.b2[j2] = __float22bfloat162_rn(make_float2(hlo * xb2, hhi * xb2));
        }
        short8 b3 = W8[(size_t)(fb0 + 24 + kk) * 64 + lane];
        accP0 = __builtin_amdgcn_mfma_f32_16x16x32_bf16(a0.s8, b3, accP0, 0, 0, 0);
        accP1 = __builtin_amdgcn_mfma_f32_16x16x32_bf16(a1.s8, b3, accP1, 0, 0, 0);
        accP2 = __builtin_amdgcn_mfma_f32_16x16x32_bf16(a2.s8, b3, accP2, 0, 0, 0);
    }

    // ---- epilogue ----
    int oo = m;
    if (oo < KVO) {
        float4 b00v = *(const float4*)(b00 + e0 + quad * 4);
        const float4* b01p = (const float4*)(b01 + (size_t)(e0 + quad * 4) * 3);
        float4 bA = b01p[0], bB = b01p[1], bC = b01p[2];
        float b01v[12] = {bA.x, bA.y, bA.z, bA.w, bB.x, bB.y, bB.z, bB.w, bC.x, bC.y, bC.z, bC.w};
        float b00a[4] = {b00v.x, b00v.y, b00v.z, b00v.w};
#pragma unroll
        for (int r = 0; r < 4; ++r) {
            int er = e0 + quad * 4 + r;
            out0[(size_t)er * KVO + oo] = b00a[r] * acc0[r] + acc2[r];
            size_t base = ((size_t)er * KVO + oo) * 3;
            out1[base + 0] = b01v[r * 3 + 0] * acc1[r] + accP0[r];
            out1[base + 1] = b01v[r * 3 + 1] * acc1[r] + accP1[r];
            out1[base + 2] = b01v[r * 3 + 2] * acc1[r] + accP2[r];
        }
    }
}

// ---------------- q projection ----------------
__global__ void k_q(int N, const float* __restrict__ xs0, const float* __restrict__ xs1,
                    const float* __restrict__ wq,
                    float* __restrict__ q0, float* __restrict__ q1) {
    int t = blockIdx.x * 256 + threadIdx.x;
    if (t >= N * 32) return;
    int n = t >> 5, comp = t & 31;
    if (comp < 8) {
        float a = 0.f;
#pragma unroll
        for (int c = 0; c < 16; ++c) a += xs0[n * 16 + c] * wq[c * 8 + comp];
        q0[n * 8 + comp] = a;
    } else {
        int idx = comp - 8, dd = idx / 3, mm = idx % 3;
        float a = 0.f;
#pragma unroll
        for (int c = 0; c < 16; ++c) a += xs1[n * 48 + c * 3 + mm] * wq[128 + c * 8 + dd];
        q1[n * 24 + dd * 3 + mm] = a;
    }
}

// ---------------- attention logits z ----------------
__global__ void k_z(int E, const int* __restrict__ dst,
                    const float* __restrict__ kv0, const float* __restrict__ kv1,
                    const float* __restrict__ q0, const float* __restrict__ q1,
                    float* __restrict__ z) {
    int e = blockIdx.x * 256 + threadIdx.x;
    if (e >= E) return;
    int n = dst[e];
    float z0 = 0.f, z1 = 0.f, z2 = 0.f, z3 = 0.f;
#pragma unroll
    for (int d = 0; d < 8; ++d) {
        float t = q0[n * 8 + d] * kv0[e * 16 + d];
#pragma unroll
        for (int m = 0; m < 3; ++m) t += q1[(n * 8 + d) * 3 + m] * kv1[(e * 16 + d) * 3 + m];
        if (d < 2) z0 += t;
        else if (d < 4) z1 += t;
        else if (d < 6) z2 += t;
        else z3 += t;
    }
    const float scale = 0.35355339059327373f;  // 1/sqrt(8)
    z[e * 4 + 0] = z0 * scale;
    z[e * 4 + 1] = z1 * scale;
    z[e * 4 + 2] = z2 * scale;
    z[e * 4 + 3] = z3 * scale;
}

// ---------------- per-node: softmax + aggregate + proj + SE3-norm ----------------
// 4 nodes per wave, 16 lanes per node; 16 nodes per block.
__global__ __launch_bounds__(256) void k_attn(
    int N,
    const int* __restrict__ rowptr, const int* __restrict__ eids,
    const float* __restrict__ z, const float* __restrict__ kv0, const float* __restrict__ kv1,
    const float* __restrict__ wproj,  // (2,24,16)
    const float* __restrict__ gamma, const float* __restrict__ beta,  // (2,16)
    float* __restrict__ xs0, float* __restrict__ xs1) {
    __shared__ float wpL[768];
    __shared__ float gL[32], btL[32];
    __shared__ float inb[16][100];  // per node: in0[24] + in1[72]
    int tid = threadIdx.x;
    for (int i = tid; i < 768; i += 256) wpL[i] = wproj[i];
    if (tid < 32) { gL[tid] = gamma[tid]; btL[tid] = beta[tid]; }
    int wave = tid >> 6, lane = tid & 63;
    int sub = lane >> 4, l16 = lane & 15;
    int nodeIdx = wave * 4 + sub;
    int n = blockIdx.x * 16 + nodeIdx;
    if (n >= N) n = N - 1;  // duplicate work, harmless (same values written)
    int base = rowptr[n], deg = rowptr[n + 1] - base;

    // phase A: per-head max (16-lane strided)
    float mx0 = -INFINITY, mx1 = -INFINITY, mx2 = -INFINITY, mx3 = -INFINITY;
    for (int j = l16; j < deg; j += 16) {
        int e = eids[base + j];
        float4 zv = *(const float4*)&z[e * 4];
        mx0 = fmaxf(mx0, zv.x); mx1 = fmaxf(mx1, zv.y);
        mx2 = fmaxf(mx2, zv.z); mx3 = fmaxf(mx3, zv.w);
    }
#pragma unroll
    for (int off = 1; off < 16; off <<= 1) {
        mx0 = fmaxf(mx0, __shfl_xor(mx0, off));
        mx1 = fmaxf(mx1, __shfl_xor(mx1, off));
        mx2 = fmaxf(mx2, __shfl_xor(mx2, off));
        mx3 = fmaxf(mx3, __shfl_xor(mx3, off));
    }
    if (!isfinite(mx0)) mx0 = 0.f;
    if (!isfinite(mx1)) mx1 = 0.f;
    if (!isfinite(mx2)) mx2 = 0.f;
    if (!isfinite(mx3)) mx3 = 0.f;

    // phase B: per-head sum
    float s0 = 0.f, s1 = 0.f, s2 = 0.f, s3 = 0.f;
    for (int j = l16; j < deg; j += 16) {
        int e = eids[base + j];
        float4 zv = *(const float4*)&z[e * 4];
        s0 += __expf(zv.x - mx0); s1 += __expf(zv.y - mx1);
        s2 += __expf(zv.z - mx2); s3 += __expf(zv.w - mx3);
    }
#pragma unroll
    for (int off = 1; off < 16; off <<= 1) {
        s0 += __shfl_xor(s0, off); s1 += __shfl_xor(s1, off);
        s2 += __shfl_xor(s2, off); s3 += __shfl_xor(s3, off);
    }
    float mxa[4] = {mx0, mx1, mx2, mx3};
    float inva[4] = {1.f / (s0 + 1e-9f), 1.f / (s1 + 1e-9f),
                     1.f / (s2 + 1e-9f), 1.f / (s3 + 1e-9f)};

    // phase 2: o-accumulation — lane owns comps c0=l16, c1=l16+16
    int c0 = l16, c1 = l16 + 16;
    int kkA = c0 >> 3, dA = c0 & 7, hA = dA >> 1;
    int kkB = c1 >> 3, dB = c1 & 7, hB = dB >> 1;
    float mA = mxa[hA], iA = inva[hA];
    float mB = mxa[hB], iB = inva[hB];
    float accA = 0.f, accB = 0.f;
    for (int j = 0; j < deg; ++j) {
        int e = eids[base + j];
        float wA = __expf(z[e * 4 + hA] - mA) * iA;
        float wB = __expf(z[e * 4 + hB] - mB) * iB;
        float vA = (kkA == 0) ? kv0[(size_t)e * 16 + 8 + dA]
                              : kv1[((size_t)e * 16 + 8 + dA) * 3 + (kkA - 1)];
        float vB = kv1[((size_t)e * 16 + 8 + dB) * 3 + (kkB - 1)];  // kkB >= 2 always
        accA += wA * vA;
        accB += wB * vB;
    }

    // stage concat([o, x]) into LDS
    float* in0 = inb[nodeIdx];
    float* in1 = in0 + 24;
    if (c0 < 8) in0[c0] = accA;
    else in1[dA * 3 + (kkA - 1)] = accA;
    in1[dB * 3 + (kkB - 1)] = accB;
    in0[8 + l16] = xs0[(size_t)n * 16 + l16];
    {
        const float* xp = xs1 + (size_t)n * 48 + l16 * 3;
        in1[24 + l16 * 3 + 0] = xp[0];
        in1[24 + l16 * 3 + 1] = xp[1];
        in1[24 + l16 * 3 + 2] = xp[2];
    }
    __syncthreads();

    // projection: each lane -> 4 outputs of its node (1 scalar + 3 vector comps)
    int c = l16;
    float y0 = 0.f;
#pragma unroll
    for (int j = 0; j < 24; ++j) y0 += in0[j] * wpL[j * 16 + c];
    float y1v[3];
#pragma unroll
    for (int mm = 0; mm < 3; ++mm) {
        float y = 0.f;
#pragma unroll
        for (int j = 0; j < 24; ++j) y += in1[j * 3 + mm] * wpL[384 + j * 16 + c];
        y1v[mm] = y;
    }
    // SE(3) norm (means/vars over the 16 channels = 16 lanes)
    float n0 = sqrtf(y0 * y0 + 1e-12f);
    float n1 = sqrtf(y1v[0] * y1v[0] + y1v[1] * y1v[1] + y1v[2] * y1v[2] + 1e-12f);
    float mu0 = n0, mu1 = n1;
#pragma unroll
    for (int off = 1; off < 16; off <<= 1) {
        mu0 += __shfl_xor(mu0, off);
        mu1 += __shfl_xor(mu1, off);
    }
    mu0 *= 0.0625f; mu1 *= 0.0625f;
    float dv0 = n0 - mu0, dv1 = n1 - mu1;
    float var0 = dv0 * dv0, var1 = dv1 * dv1;
#pragma unroll
    for (int off = 1; off < 16; off <<= 1) {
        var0 += __shfl_xor(var0, off);
        var1 += __shfl_xor(var1, off);
    }
    var0 *= 0.0625f; var1 *= 0.0625f;
    float ln0 = dv0 * rsqrtf(var0 + 1e-5f) * gL[c] + btL[c];
    float ln1 = dv1 * rsqrtf(var1 + 1e-5f) * gL[16 + c] + btL[16 + c];
    float fac0 = fmaxf(ln0, 0.f) / (n0 + 1e-3f);
    float fac1 = fmaxf(ln1, 0.f) / (n1 + 1e-3f);
    xs0[(size_t)n * 16 + c] = y0 * fac0;
    float* xo = xs1 + (size_t)n * 48 + c * 3;
    xo[0] = y1v[0] * fac1;
    xo[1] = y1v[1] * fac1;
    xo[2] = y1v[2] * fac1;
}

// ---------------- final output: segment-sum(m) + x @ wself ----------------
// 4 nodes per wave, 16 lanes per node.
__global__ __launch_bounds__(256) void k_out(
    int N,
    const int* __restrict__ rowptr, const int* __restrict__ eids,
    const float* __restrict__ m0f, const float* __restrict__ m1f,
    const float* __restrict__ xs0, const float* __restrict__ xs1,
    const float* __restrict__ wself,  // (2,16,8)
    float* __restrict__ out) {
    int tid = threadIdx.x;
    int wave = tid >> 6, lane = tid & 63;
    int sub = lane >> 4, l16 = lane & 15;
    int n = blockIdx.x * 16 + wave * 4 + sub;
    if (n >= N) n = N - 1;
    int base = rowptr[n], deg = rowptr[n + 1] - base;

    int c0 = l16, c1 = l16 + 16;
    int kkA = c0 >> 3, dA = c0 & 7;
    int kkB = c1 >> 3, dB = c1 & 7;
    float accA = 0.f, accB = 0.f;
    for (int j = 0; j < deg; ++j) {
        int e = eids[base + j];
        accA += (kkA == 0) ? m0f[(size_t)e * 8 + dA]
                           : m1f[((size_t)e * 8 + dA) * 3 + (kkA - 1)];
        accB += m1f[((size_t)e * 8 + dB) * 3 + (kkB - 1)];
    }
    if (kkA == 0) {
#pragma unroll
        for (int c = 0; c < 16; ++c) accA += xs0[(size_t)n * 16 + c] * wself[c * 8 + dA];
    } else {
#pragma unroll
        for (int c = 0; c < 16; ++c)
            accA += xs1[(size_t)n * 48 + c * 3 + (kkA - 1)] * wself[128 + c * 8 + dA];
    }
    {
        int mm = kkB - 1;
#pragma unroll
        for (int c = 0; c < 16; ++c)
            accB += xs1[(size_t)n * 48 + c * 3 + mm] * wself[128 + c * 8 + dB];
    }
    out[(size_t)n * 32 + ((kkA == 0) ? dA : (8 + dA * 3 + (kkA - 1)))] = accA;
    out[(size_t)n * 32 + (8 + dB * 3 + (kkB - 1))] = accB;
}

// ---------------------------------------------------------------------------
extern "C" void kernel_launch(void* const* d_in, const int* in_sizes, int n_in,
                              void* d_out, int out_size, void* d_ws, size_t ws_size,
                              hipStream_t stream) {
    const float* x0 = (const float*)d_in[0];
    const float* x1 = (const float*)d_in[1];
    const float* ef = (const float*)d_in[2];
    const float* b00 = (const float*)d_in[3];
    const float* b01 = (const float*)d_in[4];
    const float* b10 = (const float*)d_in[5];
    const float* b11 = (const float*)d_in[6];
    const float* kvw1 = (const float*)d_in[7];    // (2,4,16,16)
    const float* kvw2n = (const float*)d_in[8];   // (2,3,16,16,16)
    const float* kvw211 = (const float*)d_in[9];  // (2,16,16,16,3)
    const float* wq = (const float*)d_in[10];     // (2,2,16,8)
    const float* wproj = (const float*)d_in[11];  // (2,2,24,16)
    const float* gam = (const float*)d_in[12];    // (2,2,16)
    const float* bet = (const float*)d_in[13];
    const float* fcw1 = (const float*)d_in[14];    // (4,16,16)
    const float* fcw2n = (const float*)d_in[15];   // (3,16,8,16)
    const float* fcw211 = (const float*)d_in[16];  // (16,8,16,3)
    const float* fcself = (const float*)d_in[17];  // (2,16,8)
    const int* esrc = (const int*)d_in[18];
    const int* edst = (const int*)d_in[19];
    int N = in_sizes[0] / 16;
    int E = in_sizes[18];
    float* out = (float*)d_out;

    float* ws = (float*)d_ws;
    size_t off = 0;
    float* xs0 = ws + off; off += (size_t)N * 16;
    float* xs1 = ws + off; off += (size_t)N * 48;
    float* q0b = ws + off; off += (size_t)N * 8;
    float* q1b = ws + off; off += (size_t)N * 24;
    float* kv0 = ws + off; off += (size_t)E * 16;   // also fc m0 (E,8)
    float* kv1 = ws + off; off += (size_t)E * 48;   // also fc m1 (E,8,3)
    float* zb = ws + off; off += (size_t)E * 4;
    int* counts = (int*)(ws + off); off += N;
    int* rowptr = (int*)(ws + off); off += N + 1;
    int* cursor = (int*)(ws + off); off += N;
    int* eids = (int*)(ws + off); off += E;
    off = (off + 3) & ~(size_t)3;
    unsigned short* Hbuf = (unsigned short*)(ws + off); off += (size_t)4 * E * 16 / 2;
    unsigned short* Wfrag = (unsigned short*)(ws + off); off += (size_t)144 * 64 * 8 / 2;

    const int tpb = 256;
    int ebl = (E + 255) / 256;
    int cblk = (E / 16 + 3) / 4;
    int nbl16 = (N + 15) / 16;

    k_prepw<<<288, tpb, 0, stream>>>(kvw2n, kvw211, fcw2n, fcw211, Wfrag);
    // CSR over edge_dst
    k_zero<<<(N + 255) / 256, tpb, 0, stream>>>(counts, N);
    k_hist<<<ebl, tpb, 0, stream>>>(edst, counts, E);
    int CH = (N + 1023) / 1024;
    k_scan<<<1, 1024, 0, stream>>>(counts, rowptr, cursor, N, CH);
    k_scatter<<<ebl, tpb, 0, stream>>>(edst, cursor, eids, E);
    k_initx<<<(N * 64 + 255) / 256, tpb, 0, stream>>>(x0, x1, xs0, xs1, N * 16, N * 48);

    for (int l = 0; l < 2; ++l) {
        k_H<<<(4 * E + 255) / 256, tpb, 0, stream>>>(E, ef, kvw1 + l * 1024, Hbuf);
        k_q<<<(N * 32 + 255) / 256, tpb, 0, stream>>>(N, xs0, xs1, wq + l * 256, q0b, q1b);
        k_conv<16><<<cblk, tpb, 0, stream>>>(E, esrc, xs0, xs1, b00, b01, b10, b11,
                                             Hbuf, Wfrag, l * 48, kv0, kv1);
        k_z<<<ebl, tpb, 0, stream>>>(E, edst, kv0, kv1, q0b, q1b, zb);
        k_attn<<<nbl16, tpb, 0, stream>>>(N, rowptr, eids, zb, kv0, kv1,
                                          wproj + l * 768, gam + l * 32, bet + l * 32, xs0, xs1);
    }
    k_H<<<(4 * E + 255) / 256, tpb, 0, stream>>>(E, ef, fcw1, Hbuf);
    k_conv<8><<<cblk, tpb, 0, stream>>>(E, esrc, xs0, xs1, b00, b01, b10, b11,
                                        Hbuf, Wfrag, 96, kv0, kv1);
    k_out<<<nbl16, tpb, 0, stream>>>(N, rowptr, eids, kv0, kv1, xs0, xs1, fcself, out);
}

// Round 5
// 354.358 us; speedup vs baseline: 5.8282x; 1.1708x over previous
//
#include <hip/hip_runtime.h>
#include <hip/hip_bf16.h>
#include <math.h>

// ---------------------------------------------------------------------------
// EquivariantNet forward — round 5.
// Transposed MFMA orientation: A = weights (m=oo), B = per-edge Y (n=edge),
// C col = edge (lane&15), row = oo (quad*4+r). This aligns C/H layouts with
// the lane's own edge, enabling: H computed in-kernel via 4 MFMAs (k_H gone),
// z computed in the conv epilogue (k_z gone), float4 epilogue stores, and
// k-half of kv never written.
// k-mapping (fams 0-2, K=256): h = quad*4+(j&3), i = 2kk+(j>>2)
// k-mapping (fam 3, K=768):    h = quad*4+(j&3), if = 2kk+(j>>2), if = i*3+f
// Shapes: N=8192, E=131072, C=16, mid=16, KV=16, ckv=8, Co=8, HEADS=4, L=2
// ---------------------------------------------------------------------------

typedef short short8 __attribute__((ext_vector_type(8)));
typedef float f32x4 __attribute__((ext_vector_type(4)));

union ABfrag {
    short8 s8;
    __hip_bfloat162 b2[4];
};

static __device__ __forceinline__ unsigned short f2bf(float f) {
    unsigned x = __float_as_uint(f);
    unsigned r = x + 0x7FFFu + ((x >> 16) & 1u);  // RNE
    return (unsigned short)(r >> 16);
}

// ---------------- CSR build over edge_dst ----------------
__global__ void k_zero(int* p, int n) {
    int i = blockIdx.x * 256 + threadIdx.x;
    if (i < n) p[i] = 0;
}

__global__ void k_hist(const int* __restrict__ dst, int* __restrict__ counts, int E) {
    int e = blockIdx.x * 256 + threadIdx.x;
    if (e < E) atomicAdd(&counts[dst[e]], 1);
}

__global__ __launch_bounds__(1024) void k_scan(const int* __restrict__ counts,
                                               int* __restrict__ rowptr,
                                               int* __restrict__ cursor,
                                               int N, int CH) {
    __shared__ int part[1024];
    int t = threadIdx.x;
    int s = 0;
    for (int i = 0; i < CH; ++i) {
        int idx = t * CH + i;
        if (idx < N) s += counts[idx];
    }
    part[t] = s;
    __syncthreads();
    for (int off = 1; off < 1024; off <<= 1) {
        int v = (t >= off) ? part[t - off] : 0;
        __syncthreads();
        part[t] += v;
        __syncthreads();
    }
    int run = (t == 0) ? 0 : part[t - 1];
    for (int i = 0; i < CH; ++i) {
        int idx = t * CH + i;
        if (idx < N) {
            rowptr[idx] = run;
            cursor[idx] = run;
            run += counts[idx];
        }
    }
    if (t == 0) rowptr[N] = part[1023];
}

__global__ void k_scatter(const int* __restrict__ dst, int* __restrict__ cursor,
                          int* __restrict__ eids, int E) {
    int e = blockIdx.x * 256 + threadIdx.x;
    if (e < E) {
        int pos = atomicAdd(&cursor[dst[e]], 1);
        eids[pos] = e;
    }
}

// ---------------- init x working copies ----------------
__global__ void k_initx(const float* __restrict__ x0, const float* __restrict__ x1,
                        float* __restrict__ xs0, float* __restrict__ xs1, int n0, int n1) {
    int i = blockIdx.x * 256 + threadIdx.x;
    if (i < n0) xs0[i] = x0[i];
    else if (i < n0 + n1) xs1[i - n0] = x1[i - n0];
}

// ---------------- ef -> bf16 copy ----------------
__global__ void k_efb(const float* __restrict__ ef, unsigned short* __restrict__ efb, int n) {
    int i = blockIdx.x * 256 + threadIdx.x;
    if (i < n) efb[i] = f2bf(ef[i]);
}

// ---------------- weight permute into A-fragment order (bf16) ----------------
// 52 frag-rows per conv (conv c base = c*52):
//   rows 0..3   : w1 A-frags, A[m=h][k=f]: value w1[pp][f=quad*8+j][h=m], quad<2 else 0
//   rows 4..27  : fams 0..2 (fam*8+kk): A[m=oo][k], h=quad*4+(j&3), i=2kk+(j>>2)
//   rows 28..51 : fam 3 (kk 0..23):     A[m=oo][k], h=quad*4+(j&3), if=2kk+(j>>2)
__global__ void k_prepw(const float* __restrict__ kvw1, const float* __restrict__ fcw1,
                        const float* __restrict__ kvw2n, const float* __restrict__ kvw211,
                        const float* __restrict__ fcw2n, const float* __restrict__ fcw211,
                        unsigned short* __restrict__ Wfrag) {
    int t = blockIdx.x * 256 + threadIdx.x;
    if (t >= 156 * 64 * 8) return;
    int j = t & 7;
    int lane = (t >> 3) & 63;
    int row = t >> 9;
    int quad = lane >> 4, m = lane & 15;
    int c = row / 52, r = row % 52;
    int KVO = (c < 2) ? 16 : 8;
    const float* w1src = (c < 2) ? (kvw1 + c * 1024) : fcw1;
    const float* w2n = (c < 2) ? (kvw2n + c * 12288) : fcw2n;
    const float* w211 = (c < 2) ? (kvw211 + c * 12288) : fcw211;
    float v = 0.f;
    if (r < 4) {
        if (quad < 2) v = w1src[r * 256 + (quad * 8 + j) * 16 + m];
    } else if (r < 28) {
        int fam = (r - 4) >> 3, kk = (r - 4) & 7;
        int h = quad * 4 + (j & 3), i = 2 * kk + (j >> 2);
        if (m < KVO) v = w2n[((fam * 16 + h) * KVO + m) * 16 + i];
    } else {
        int kk = r - 28;
        int h = quad * 4 + (j & 3);
        int ifx = 2 * kk + (j >> 2);
        int i = ifx / 3, f = ifx % 3;
        if (m < KVO) v = w211[((h * KVO + m) * 16 + i) * 3 + f];
    }
    Wfrag[t] = f2bf(v);
}

// ---------------- fused MFMA conv (+H, +z) ----------------
template <int KVO, bool DO_Z>
__global__ __launch_bounds__(256) void k_conv(
    int E,
    const int* __restrict__ src, const int* __restrict__ dst,
    const float* __restrict__ xs0, const float* __restrict__ xs1,
    const float* __restrict__ b00, const float* __restrict__ b01,
    const float* __restrict__ b10, const float* __restrict__ b11,
    const unsigned short* __restrict__ efb,    // (E,16) bf16
    const unsigned short* __restrict__ Wfrag,  // frag-ordered weights
    int base,                                  // frag-row base for this conv
    const float* __restrict__ q0, const float* __restrict__ q1,
    float* __restrict__ out0, float* __restrict__ out1, float* __restrict__ zb)
{
    __shared__ float xBL[4][16 * 148];  // per-wave: [m][p*48 + if], stride 148
    int tid = threadIdx.x;
    int wave = tid >> 6, lane = tid & 63;
    int tile = blockIdx.x * 4 + wave;
    if (tile * 16 >= E) return;
    int m = lane & 15, quad = lane >> 4;
    int e0 = tile * 16;
    int me = e0 + m;
    int s = src[me];
    float* xw = xBL[wave];
    const short8* W8 = (const short8*)Wfrag;

    // ---- xB[p][if] = sum_q x1[i][q]*b11[p][q][f]; this quad covers i in [quad*4, quad*4+4) ----
    {
        float x1c[12];
        const float4* xp = (const float4*)(xs1 + (size_t)s * 48 + quad * 12);
#pragma unroll
        for (int cc = 0; cc < 3; ++cc) {
            float4 v = xp[cc];
            x1c[cc * 4 + 0] = v.x; x1c[cc * 4 + 1] = v.y;
            x1c[cc * 4 + 2] = v.z; x1c[cc * 4 + 3] = v.w;
        }
        float b11r[27];
#pragma unroll
        for (int k = 0; k < 27; ++k) b11r[k] = b11[(size_t)me * 27 + k];
#pragma unroll
        for (int p = 0; p < 3; ++p) {
            float vals[12];
#pragma unroll
            for (int i2 = 0; i2 < 4; ++i2) {
#pragma unroll
                for (int f = 0; f < 3; ++f) {
                    float a = 0.f;
#pragma unroll
                    for (int q = 0; q < 3; ++q) a += x1c[i2 * 3 + q] * b11r[p * 9 + q * 3 + f];
                    vals[i2 * 3 + f] = a;
                }
            }
#pragma unroll
            for (int cc = 0; cc < 3; ++cc) {
                float4 v = make_float4(vals[cc * 4 + 0], vals[cc * 4 + 1],
                                       vals[cc * 4 + 2], vals[cc * 4 + 3]);
                *(float4*)&xw[m * 148 + p * 48 + quad * 12 + cc * 4] = v;
            }
        }
    }
    __syncthreads();

    // ---- x0 row (16) and t10 row (16) in registers ----
    float x0r[16];
    {
        const float4* p = (const float4*)(xs0 + (size_t)s * 16);
#pragma unroll
        for (int k = 0; k < 4; ++k) {
            float4 v = p[k];
            x0r[k * 4 + 0] = v.x; x0r[k * 4 + 1] = v.y;
            x0r[k * 4 + 2] = v.z; x0r[k * 4 + 3] = v.w;
        }
    }
    float t10[16];
    {
        float bq0 = b10[(size_t)me * 3 + 0], bq1 = b10[(size_t)me * 3 + 1],
              bq2 = b10[(size_t)me * 3 + 2];
        const float4* xp = (const float4*)(xs1 + (size_t)s * 48);
#pragma unroll
        for (int g = 0; g < 4; ++g) {
            float4 a = xp[g * 3 + 0], b = xp[g * 3 + 1], cc = xp[g * 3 + 2];
            float xf[12] = {a.x, a.y, a.z, a.w, b.x, b.y, b.z, b.w, cc.x, cc.y, cc.z, cc.w};
#pragma unroll
            for (int i2 = 0; i2 < 4; ++i2)
                t10[g * 4 + i2] = bq0 * xf[i2 * 3] + bq1 * xf[i2 * 3 + 1] + bq2 * xf[i2 * 3 + 2];
        }
    }

    // ---- H via 4 MFMAs: C[row=h=quad*4+r][col=edge=m] ----
    float Hp[4][4];
    {
        short8 efr = {0, 0, 0, 0, 0, 0, 0, 0};
        if (quad < 2) efr = *(const short8*)(efb + (size_t)me * 16 + quad * 8);
        f32x4 z4 = {0.f, 0.f, 0.f, 0.f};
#pragma unroll
        for (int pp = 0; pp < 4; ++pp) {
            short8 w1f = W8[(size_t)(base + pp) * 64 + lane];
            f32x4 hacc = __builtin_amdgcn_mfma_f32_16x16x32_bf16(w1f, efr, z4, 0, 0, 0);
#pragma unroll
            for (int r = 0; r < 4; ++r) Hp[pp][r] = fmaxf(hacc[r], 0.f);
        }
    }

    f32x4 acc0 = {0.f, 0.f, 0.f, 0.f}, acc1 = acc0, acc2 = acc0;
    f32x4 accP0 = acc0, accP1 = acc0, accP2 = acc0;

    // ---- loop1: fams 0,1,2 (K=256): Y[j] = H[j&3] * x[2kk+(j>>2)] ----
#pragma unroll
    for (int kk = 0; kk < 8; ++kk) {
        float xa = x0r[2 * kk], xb_ = x0r[2 * kk + 1];
        float ta = t10[2 * kk], tb_ = t10[2 * kk + 1];
        ABfrag a0, a1, a2;
        a0.b2[0] = __float22bfloat162_rn(make_float2(Hp[0][0] * xa, Hp[0][1] * xa));
        a0.b2[1] = __float22bfloat162_rn(make_float2(Hp[0][2] * xa, Hp[0][3] * xa));
        a0.b2[2] = __float22bfloat162_rn(make_float2(Hp[0][0] * xb_, Hp[0][1] * xb_));
        a0.b2[3] = __float22bfloat162_rn(make_float2(Hp[0][2] * xb_, Hp[0][3] * xb_));
        a1.b2[0] = __float22bfloat162_rn(make_float2(Hp[1][0] * xa, Hp[1][1] * xa));
        a1.b2[1] = __float22bfloat162_rn(make_float2(Hp[1][2] * xa, Hp[1][3] * xa));
        a1.b2[2] = __float22bfloat162_rn(make_float2(Hp[1][0] * xb_, Hp[1][1] * xb_));
        a1.b2[3] = __float22bfloat162_rn(make_float2(Hp[1][2] * xb_, Hp[1][3] * xb_));
        a2.b2[0] = __float22bfloat162_rn(make_float2(Hp[2][0] * ta, Hp[2][1] * ta));
        a2.b2[1] = __float22bfloat162_rn(make_float2(Hp[2][2] * ta, Hp[2][3] * ta));
        a2.b2[2] = __float22bfloat162_rn(make_float2(Hp[2][0] * tb_, Hp[2][1] * tb_));
        a2.b2[3] = __float22bfloat162_rn(make_float2(Hp[2][2] * tb_, Hp[2][3] * tb_));
        short8 w0 = W8[(size_t)(base + 4 + kk) * 64 + lane];
        short8 w1f = W8[(size_t)(base + 4 + 8 + kk) * 64 + lane];
        short8 w2f = W8[(size_t)(base + 4 + 16 + kk) * 64 + lane];
        acc0 = __builtin_amdgcn_mfma_f32_16x16x32_bf16(w0, a0.s8, acc0, 0, 0, 0);
        acc1 = __builtin_amdgcn_mfma_f32_16x16x32_bf16(w1f, a1.s8, acc1, 0, 0, 0);
        acc2 = __builtin_amdgcn_mfma_f32_16x16x32_bf16(w2f, a2.s8, acc2, 0, 0, 0);
    }

    // ---- loop2: fam3 (K=768), 3 p-GEMMs share the W frag ----
#pragma unroll
    for (int kko = 0; kko < 12; ++kko) {
        float4 xb0 = *(const float4*)&xw[m * 148 + 0 * 48 + 4 * kko];
        float4 xb1 = *(const float4*)&xw[m * 148 + 1 * 48 + 4 * kko];
        float4 xb2 = *(const float4*)&xw[m * 148 + 2 * 48 + 4 * kko];
        float x0a[4] = {xb0.x, xb0.y, xb0.z, xb0.w};
        float x1a[4] = {xb1.x, xb1.y, xb1.z, xb1.w};
        float x2a[4] = {xb2.x, xb2.y, xb2.z, xb2.w};
#pragma unroll
        for (int t = 0; t < 2; ++t) {
            float p0a = x0a[2 * t], p0b = x0a[2 * t + 1];
            float p1a = x1a[2 * t], p1b = x1a[2 * t + 1];
            float p2a = x2a[2 * t], p2b = x2a[2 * t + 1];
            ABfrag a0, a1, a2;
            a0.b2[0] = __float22bfloat162_rn(make_float2(Hp[3][0] * p0a, Hp[3][1] * p0a));
            a0.b2[1] = __float22bfloat162_rn(make_float2(Hp[3][2] * p0a, Hp[3][3] * p0a));
            a0.b2[2] = __float22bfloat162_rn(make_float2(Hp[3][0] * p0b, Hp[3][1] * p0b));
            a0.b2[3] = __float22bfloat162_rn(make_float2(Hp[3][2] * p0b, Hp[3][3] * p0b));
            a1.b2[0] = __float22bfloat162_rn(make_float2(Hp[3][0] * p1a, Hp[3][1] * p1a));
            a1.b2[1] = __float22bfloat162_rn(make_float2(Hp[3][2] * p1a, Hp[3][3] * p1a));
            a1.b2[2] = __float22bfloat162_rn(make_float2(Hp[3][0] * p1b, Hp[3][1] * p1b));
            a1.b2[3] = __float22bfloat162_rn(make_float2(Hp[3][2] * p1b, Hp[3][3] * p1b));
            a2.b2[0] = __float22bfloat162_rn(make_float2(Hp[3][0] * p2a, Hp[3][1] * p2a));
            a2.b2[1] = __float22bfloat162_rn(make_float2(Hp[3][2] * p2a, Hp[3][3] * p2a));
            a2.b2[2] = __float22bfloat162_rn(make_float2(Hp[3][0] * p2b, Hp[3][1] * p2b));
            a2.b2[3] = __float22bfloat162_rn(make_float2(Hp[3][2] * p2b, Hp[3][3] * p2b));
            short8 wf = W8[(size_t)(base + 28 + 2 * kko + t) * 64 + lane];
            accP0 = __builtin_amdgcn_mfma_f32_16x16x32_bf16(wf, a0.s8, accP0, 0, 0, 0);
            accP1 = __builtin_amdgcn_mfma_f32_16x16x32_bf16(wf, a1.s8, accP1, 0, 0, 0);
            accP2 = __builtin_amdgcn_mfma_f32_16x16x32_bf16(wf, a2.s8, accP2, 0, 0, 0);
        }
    }

    // ---- epilogue: lane holds oo = quad*4+r (r=0..3) for edge me ----
    float b00r = b00[me];
    float b01r0 = b01[(size_t)me * 3 + 0], b01r1 = b01[(size_t)me * 3 + 1],
          b01r2 = b01[(size_t)me * 3 + 2];
    float o0v[4], o1v[4][3];
#pragma unroll
    for (int r = 0; r < 4; ++r) {
        o0v[r] = b00r * acc0[r] + acc2[r];
        o1v[r][0] = b01r0 * acc1[r] + accP0[r];
        o1v[r][1] = b01r1 * acc1[r] + accP1[r];
        o1v[r][2] = b01r2 * acc1[r] + accP2[r];
    }
    bool doStore = DO_Z ? (quad >= 2) : (quad * 4 < KVO);
    if (doStore) {
        *(float4*)&out0[(size_t)me * KVO + quad * 4] =
            make_float4(o0v[0], o0v[1], o0v[2], o0v[3]);
        float* p1 = out1 + ((size_t)me * KVO + quad * 4) * 3;
        *(float4*)&p1[0] = make_float4(o1v[0][0], o1v[0][1], o1v[0][2], o1v[1][0]);
        *(float4*)&p1[4] = make_float4(o1v[1][1], o1v[1][2], o1v[2][0], o1v[2][1]);
        *(float4*)&p1[8] = make_float4(o1v[2][2], o1v[3][0], o1v[3][1], o1v[3][2]);
    }
    if (DO_Z && quad < 2) {
        int n = dst[me];
        float4 q0v = *(const float4*)&q0[(size_t)n * 8 + quad * 4];
        const float4* q1p = (const float4*)&q1[(size_t)n * 24 + quad * 12];
        float4 qa = q1p[0], qb = q1p[1], qc = q1p[2];
        float q1f[12] = {qa.x, qa.y, qa.z, qa.w, qb.x, qb.y, qb.z, qb.w,
                         qc.x, qc.y, qc.z, qc.w};
        float q0f[4] = {q0v.x, q0v.y, q0v.z, q0v.w};
        float zh0 = 0.f, zh1 = 0.f;
#pragma unroll
        for (int r = 0; r < 4; ++r) {
            float tt = q0f[r] * o0v[r] + q1f[r * 3 + 0] * o1v[r][0] +
                       q1f[r * 3 + 1] * o1v[r][1] + q1f[r * 3 + 2] * o1v[r][2];
            if (r < 2) zh0 += tt;
            else zh1 += tt;
        }
        const float scale = 0.35355339059327373f;  // 1/sqrt(8)
        *(float2*)&zb[(size_t)me * 4 + quad * 2] = make_float2(zh0 * scale, zh1 * scale);
    }
}

// ---------------- q projection ----------------
__global__ void k_q(int N, const float* __restrict__ xs0, const float* __restrict__ xs1,
                    const float* __restrict__ wq,
                    float* __restrict__ q0, float* __restrict__ q1) {
    int t = blockIdx.x * 256 + threadIdx.x;
    if (t >= N * 32) return;
    int n = t >> 5, comp = t & 31;
    if (comp < 8) {
        float a = 0.f;
#pragma unroll
        for (int c = 0; c < 16; ++c) a += xs0[n * 16 + c] * wq[c * 8 + comp];
        q0[n * 8 + comp] = a;
    } else {
        int idx = comp - 8, dd = idx / 3, mm = idx % 3;
        float a = 0.f;
#pragma unroll
        for (int c = 0; c < 16; ++c) a += xs1[n * 48 + c * 3 + mm] * wq[128 + c * 8 + dd];
        q1[n * 24 + dd * 3 + mm] = a;
    }
}

// ---------------- per-node: softmax + aggregate + proj + SE3-norm ----------------
// 4 nodes per wave, 16 lanes per node; 16 nodes per block.
__global__ __launch_bounds__(256) void k_attn(
    int N,
    const int* __restrict__ rowptr, const int* __restrict__ eids,
    const float* __restrict__ z, const float* __restrict__ kv0, const float* __restrict__ kv1,
    const float* __restrict__ wproj,  // (2,24,16)
    const float* __restrict__ gamma, const float* __restrict__ beta,  // (2,16)
    float* __restrict__ xs0, float* __restrict__ xs1) {
    __shared__ float wpL[768];
    __shared__ float gL[32], btL[32];
    __shared__ float inb[16][100];  // per node: in0[24] + in1[72]
    int tid = threadIdx.x;
    for (int i = tid; i < 768; i += 256) wpL[i] = wproj[i];
    if (tid < 32) { gL[tid] = gamma[tid]; btL[tid] = beta[tid]; }
    int wave = tid >> 6, lane = tid & 63;
    int sub = lane >> 4, l16 = lane & 15;
    int nodeIdx = wave * 4 + sub;
    int n = blockIdx.x * 16 + nodeIdx;
    if (n >= N) n = N - 1;
    int base = rowptr[n], deg = rowptr[n + 1] - base;

    float mx0 = -INFINITY, mx1 = -INFINITY, mx2 = -INFINITY, mx3 = -INFINITY;
    for (int j = l16; j < deg; j += 16) {
        int e = eids[base + j];
        float4 zv = *(const float4*)&z[e * 4];
        mx0 = fmaxf(mx0, zv.x); mx1 = fmaxf(mx1, zv.y);
        mx2 = fmaxf(mx2, zv.z); mx3 = fmaxf(mx3, zv.w);
    }
#pragma unroll
    for (int off = 1; off < 16; off <<= 1) {
        mx0 = fmaxf(mx0, __shfl_xor(mx0, off));
        mx1 = fmaxf(mx1, __shfl_xor(mx1, off));
        mx2 = fmaxf(mx2, __shfl_xor(mx2, off));
        mx3 = fmaxf(mx3, __shfl_xor(mx3, off));
    }
    if (!isfinite(mx0)) mx0 = 0.f;
    if (!isfinite(mx1)) mx1 = 0.f;
    if (!isfinite(mx2)) mx2 = 0.f;
    if (!isfinite(mx3)) mx3 = 0.f;

    float s0 = 0.f, s1 = 0.f, s2 = 0.f, s3 = 0.f;
    for (int j = l16; j < deg; j += 16) {
        int e = eids[base + j];
        float4 zv = *(const float4*)&z[e * 4];
        s0 += __expf(zv.x - mx0); s1 += __expf(zv.y - mx1);
        s2 += __expf(zv.z - mx2); s3 += __expf(zv.w - mx3);
    }
#pragma unroll
    for (int off = 1; off < 16; off <<= 1) {
        s0 += __shfl_xor(s0, off); s1 += __shfl_xor(s1, off);
        s2 += __shfl_xor(s2, off); s3 += __shfl_xor(s3, off);
    }
    float mxa[4] = {mx0, mx1, mx2, mx3};
    float inva[4] = {1.f / (s0 + 1e-9f), 1.f / (s1 + 1e-9f),
                     1.f / (s2 + 1e-9f), 1.f / (s3 + 1e-9f)};

    int c0 = l16, c1 = l16 + 16;
    int kkA = c0 >> 3, dA = c0 & 7, hA = dA >> 1;
    int kkB = c1 >> 3, dB = c1 & 7, hB = dB >> 1;
    float mA = mxa[hA], iA = inva[hA];
    float mB = mxa[hB], iB = inva[hB];
    float accA = 0.f, accB = 0.f;
    for (int j = 0; j < deg; ++j) {
        int e = eids[base + j];
        float wA = __expf(z[e * 4 + hA] - mA) * iA;
        float wB = __expf(z[e * 4 + hB] - mB) * iB;
        float vA = (kkA == 0) ? kv0[(size_t)e * 16 + 8 + dA]
                              : kv1[((size_t)e * 16 + 8 + dA) * 3 + (kkA - 1)];
        float vB = kv1[((size_t)e * 16 + 8 + dB) * 3 + (kkB - 1)];
        accA += wA * vA;
        accB += wB * vB;
    }

    float* in0 = inb[nodeIdx];
    float* in1 = in0 + 24;
    if (c0 < 8) in0[c0] = accA;
    else in1[dA * 3 + (kkA - 1)] = accA;
    in1[dB * 3 + (kkB - 1)] = accB;
    in0[8 + l16] = xs0[(size_t)n * 16 + l16];
    {
        const float* xp = xs1 + (size_t)n * 48 + l16 * 3;
        in1[24 + l16 * 3 + 0] = xp[0];
        in1[24 + l16 * 3 + 1] = xp[1];
        in1[24 + l16 * 3 + 2] = xp[2];
    }
    __syncthreads();

    int c = l16;
    float y0 = 0.f;
#pragma unroll
    for (int j = 0; j < 24; ++j) y0 += in0[j] * wpL[j * 16 + c];
    float y1v[3];
#pragma unroll
    for (int mm = 0; mm < 3; ++mm) {
        float y = 0.f;
#pragma unroll
        for (int j = 0; j < 24; ++j) y += in1[j * 3 + mm] * wpL[384 + j * 16 + c];
        y1v[mm] = y;
    }
    float n0 = sqrtf(y0 * y0 + 1e-12f);
    float n1 = sqrtf(y1v[0] * y1v[0] + y1v[1] * y1v[1] + y1v[2] * y1v[2] + 1e-12f);
    float mu0 = n0, mu1 = n1;
#pragma unroll
    for (int off = 1; off < 16; off <<= 1) {
        mu0 += __shfl_xor(mu0, off);
        mu1 += __shfl_xor(mu1, off);
    }
    mu0 *= 0.0625f; mu1 *= 0.0625f;
    float dv0 = n0 - mu0, dv1 = n1 - mu1;
    float var0 = dv0 * dv0, var1 = dv1 * dv1;
#pragma unroll
    for (int off = 1; off < 16; off <<= 1) {
        var0 += __shfl_xor(var0, off);
        var1 += __shfl_xor(var1, off);
    }
    var0 *= 0.0625f; var1 *= 0.0625f;
    float ln0 = dv0 * rsqrtf(var0 + 1e-5f) * gL[c] + btL[c];
    float ln1 = dv1 * rsqrtf(var1 + 1e-5f) * gL[16 + c] + btL[16 + c];
    float fac0 = fmaxf(ln0, 0.f) / (n0 + 1e-3f);
    float fac1 = fmaxf(ln1, 0.f) / (n1 + 1e-3f);
    xs0[(size_t)n * 16 + c] = y0 * fac0;
    float* xo = xs1 + (size_t)n * 48 + c * 3;
    xo[0] = y1v[0] * fac1;
    xo[1] = y1v[1] * fac1;
    xo[2] = y1v[2] * fac1;
}

// ---------------- final output: segment-sum(m) + x @ wself ----------------
__global__ __launch_bounds__(256) void k_out(
    int N,
    const int* __restrict__ rowptr, const int* __restrict__ eids,
    const float* __restrict__ m0f, const float* __restrict__ m1f,
    const float* __restrict__ xs0, const float* __restrict__ xs1,
    const float* __restrict__ wself,  // (2,16,8)
    float* __restrict__ out) {
    int tid = threadIdx.x;
    int wave = tid >> 6, lane = tid & 63;
    int sub = lane >> 4, l16 = lane & 15;
    int n = blockIdx.x * 16 + wave * 4 + sub;
    if (n >= N) n = N - 1;
    int base = rowptr[n], deg = rowptr[n + 1] - base;

    int c0 = l16, c1 = l16 + 16;
    int kkA = c0 >> 3, dA = c0 & 7;
    int kkB = c1 >> 3, dB = c1 & 7;
    float accA = 0.f, accB = 0.f;
    for (int j = 0; j < deg; ++j) {
        int e = eids[base + j];
        accA += (kkA == 0) ? m0f[(size_t)e * 8 + dA]
                           : m1f[((size_t)e * 8 + dA) * 3 + (kkA - 1)];
        accB += m1f[((size_t)e * 8 + dB) * 3 + (kkB - 1)];
    }
    if (kkA == 0) {
#pragma unroll
        for (int c = 0; c < 16; ++c) accA += xs0[(size_t)n * 16 + c] * wself[c * 8 + dA];
    } else {
#pragma unroll
        for (int c = 0; c < 16; ++c)
            accA += xs1[(size_t)n * 48 + c * 3 + (kkA - 1)] * wself[128 + c * 8 + dA];
    }
    {
        int mm = kkB - 1;
#pragma unroll
        for (int c = 0; c < 16; ++c)
            accB += xs1[(size_t)n * 48 + c * 3 + mm] * wself[128 + c * 8 + dB];
    }
    out[(size_t)n * 32 + ((kkA == 0) ? dA : (8 + dA * 3 + (kkA - 1)))] = accA;
    out[(size_t)n * 32 + (8 + dB * 3 + (kkB - 1))] = accB;
}

// ---------------------------------------------------------------------------
extern "C" void kernel_launch(void* const* d_in, const int* in_sizes, int n_in,
                              void* d_out, int out_size, void* d_ws, size_t ws_size,
                              hipStream_t stream) {
    const float* x0 = (const float*)d_in[0];
    const float* x1 = (const float*)d_in[1];
    const float* ef = (const float*)d_in[2];
    const float* b00 = (const float*)d_in[3];
    const float* b01 = (const float*)d_in[4];
    const float* b10 = (const float*)d_in[5];
    const float* b11 = (const float*)d_in[6];
    const float* kvw1 = (const float*)d_in[7];    // (2,4,16,16)
    const float* kvw2n = (const float*)d_in[8];   // (2,3,16,16,16)
    const float* kvw211 = (const float*)d_in[9];  // (2,16,16,16,3)
    const float* wq = (const float*)d_in[10];     // (2,2,16,8)
    const float* wproj = (const float*)d_in[11];  // (2,2,24,16)
    const float* gam = (const float*)d_in[12];    // (2,2,16)
    const float* bet = (const float*)d_in[13];
    const float* fcw1 = (const float*)d_in[14];    // (4,16,16)
    const float* fcw2n = (const float*)d_in[15];   // (3,16,8,16)
    const float* fcw211 = (const float*)d_in[16];  // (16,8,16,3)
    const float* fcself = (const float*)d_in[17];  // (2,16,8)
    const int* esrc = (const int*)d_in[18];
    const int* edst = (const int*)d_in[19];
    int N = in_sizes[0] / 16;
    int E = in_sizes[18];
    float* out = (float*)d_out;

    float* ws = (float*)d_ws;
    size_t off = 0;
    float* xs0 = ws + off; off += (size_t)N * 16;
    float* xs1 = ws + off; off += (size_t)N * 48;
    float* q0b = ws + off; off += (size_t)N * 8;
    float* q1b = ws + off; off += (size_t)N * 24;
    float* kv0 = ws + off; off += (size_t)E * 16;   // also fc m0 (E,8)
    float* kv1 = ws + off; off += (size_t)E * 48;   // also fc m1 (E,8,3)
    float* zb = ws + off; off += (size_t)E * 4;
    int* counts = (int*)(ws + off); off += N;
    int* rowptr = (int*)(ws + off); off += N + 1;
    int* cursor = (int*)(ws + off); off += N;
    int* eids = (int*)(ws + off); off += E;
    off = (off + 3) & ~(size_t)3;
    unsigned short* efb = (unsigned short*)(ws + off); off += (size_t)E * 16 / 2;
    unsigned short* Wfrag = (unsigned short*)(ws + off); off += (size_t)156 * 64 * 8 / 2;

    const int tpb = 256;
    int ebl = (E + 255) / 256;
    int cblk = (E / 16 + 3) / 4;
    int nbl16 = (N + 15) / 16;

    k_prepw<<<(156 * 512 + 255) / 256, tpb, 0, stream>>>(kvw1, fcw1, kvw2n, kvw211,
                                                         fcw2n, fcw211, Wfrag);
    k_efb<<<(E * 16 + 255) / 256, tpb, 0, stream>>>(ef, efb, E * 16);
    // CSR over edge_dst
    k_zero<<<(N + 255) / 256, tpb, 0, stream>>>(counts, N);
    k_hist<<<ebl, tpb, 0, stream>>>(edst, counts, E);
    int CH = (N + 1023) / 1024;
    k_scan<<<1, 1024, 0, stream>>>(counts, rowptr, cursor, N, CH);
    k_scatter<<<ebl, tpb, 0, stream>>>(edst, cursor, eids, E);
    k_initx<<<(N * 64 + 255) / 256, tpb, 0, stream>>>(x0, x1, xs0, xs1, N * 16, N * 48);

    for (int l = 0; l < 2; ++l) {
        k_q<<<(N * 32 + 255) / 256, tpb, 0, stream>>>(N, xs0, xs1, wq + l * 256, q0b, q1b);
        k_conv<16, true><<<cblk, tpb, 0, stream>>>(E, esrc, edst, xs0, xs1, b00, b01, b10, b11,
                                                   efb, Wfrag, l * 52, q0b, q1b, kv0, kv1, zb);
        k_attn<<<nbl16, tpb, 0, stream>>>(N, rowptr, eids, zb, kv0, kv1,
                                          wproj + l * 768, gam + l * 32, bet + l * 32, xs0, xs1);
    }
    k_conv<8, false><<<cblk, tpb, 0, stream>>>(E, esrc, edst, xs0, xs1, b00, b01, b10, b11,
                                               efb, Wfrag, 2 * 52, q0b, q1b, kv0, kv1, zb);
    k_out<<<nbl16, tpb, 0, stream>>>(N, rowptr, eids, kv0, kv1, xs0, xs1, fcself, out);
}

// Round 6
// 295.156 us; speedup vs baseline: 6.9972x; 1.2006x over previous
//
#include <hip/hip_runtime.h>
#include <hip/hip_fp16.h>
#include <math.h>

// ---------------------------------------------------------------------------
// EquivariantNet forward — round 6.
// r5 structure + (1) f16 MFMA path with v_pk_mul_f16 A-builds (no cvt chain),
// (2) CSR-ordered z/vrow payloads written from conv (pos_of_edge), making all
// attention/output reads coalesced, (3) de-duplicated expf via per-chunk LDS
// alpha, (4) fused init kernels + memset (13 launches).
// Shapes: N=8192, E=131072, C=16, mid=16, KV=16, ckv=8, Co=8, HEADS=4, L=2
// ---------------------------------------------------------------------------

typedef _Float16 half8 __attribute__((ext_vector_type(8)));
typedef float f32x4 __attribute__((ext_vector_type(4)));

union AF {
    half8 h8;
    __half2 h2[4];
};
union U32h2 {
    unsigned u;
    __half2 h;
};

// ---------------- CSR build over edge_dst ----------------
__global__ void k_hist(const int* __restrict__ dst, int* __restrict__ counts, int E) {
    int e = blockIdx.x * 256 + threadIdx.x;
    if (e < E) atomicAdd(&counts[dst[e]], 1);
}

__global__ __launch_bounds__(1024) void k_scan(const int* __restrict__ counts,
                                               int* __restrict__ rowptr,
                                               int* __restrict__ cursor,
                                               int N, int CH) {
    __shared__ int part[1024];
    int t = threadIdx.x;
    int s = 0;
    for (int i = 0; i < CH; ++i) {
        int idx = t * CH + i;
        if (idx < N) s += counts[idx];
    }
    part[t] = s;
    __syncthreads();
    for (int off = 1; off < 1024; off <<= 1) {
        int v = (t >= off) ? part[t - off] : 0;
        __syncthreads();
        part[t] += v;
        __syncthreads();
    }
    int run = (t == 0) ? 0 : part[t - 1];
    for (int i = 0; i < CH; ++i) {
        int idx = t * CH + i;
        if (idx < N) {
            rowptr[idx] = run;
            cursor[idx] = run;
            run += counts[idx];
        }
    }
    if (t == 0) rowptr[N] = part[1023];
}

__global__ void k_scatter(const int* __restrict__ dst, int* __restrict__ cursor,
                          int* __restrict__ pose, int E) {
    int e = blockIdx.x * 256 + threadIdx.x;
    if (e < E) {
        int pos = atomicAdd(&cursor[dst[e]], 1);
        pose[e] = pos;
    }
}

// ---------------- fused init: xs copies + ef->f16 ----------------
__global__ void k_misc(const float* __restrict__ x0, const float* __restrict__ x1,
                       const float* __restrict__ ef,
                       float* __restrict__ xs0, float* __restrict__ xs1,
                       unsigned short* __restrict__ efh, int n0, int n1, int n2) {
    int i = blockIdx.x * 256 + threadIdx.x;
    if (i < n0) xs0[i] = x0[i];
    else if (i < n0 + n1) xs1[i - n0] = x1[i - n0];
    else if (i < n0 + n1 + n2) {
        int k = i - n0 - n1;
        efh[k] = __half_as_ushort(__float2half(ef[k]));
    }
}

// ---------------- weight permute into A-fragment order (f16) ----------------
// 52 frag-rows per conv (conv c base = c*52):
//   rows 0..3   : w1 A-frags, A[m=h][k=f]: w1[pp][f=quad*8+j][h=m], quad<2 else 0
//   rows 4..27  : fams 0..2 (fam*8+kk): A[m=oo][k], h=quad*4+(j&3), i=2kk+(j>>2)
//   rows 28..51 : fam 3 (kk 0..23):     A[m=oo][k], h=quad*4+(j&3), if=2kk+(j>>2)
__global__ void k_prepw(const float* __restrict__ kvw1, const float* __restrict__ fcw1,
                        const float* __restrict__ kvw2n, const float* __restrict__ kvw211,
                        const float* __restrict__ fcw2n, const float* __restrict__ fcw211,
                        unsigned short* __restrict__ Wfrag) {
    int t = blockIdx.x * 256 + threadIdx.x;
    if (t >= 156 * 64 * 8) return;
    int j = t & 7;
    int lane = (t >> 3) & 63;
    int row = t >> 9;
    int quad = lane >> 4, m = lane & 15;
    int c = row / 52, r = row % 52;
    int KVO = (c < 2) ? 16 : 8;
    const float* w1src = (c < 2) ? (kvw1 + c * 1024) : fcw1;
    const float* w2n = (c < 2) ? (kvw2n + c * 12288) : fcw2n;
    const float* w211 = (c < 2) ? (kvw211 + c * 12288) : fcw211;
    float v = 0.f;
    if (r < 4) {
        if (quad < 2) v = w1src[r * 256 + (quad * 8 + j) * 16 + m];
    } else if (r < 28) {
        int fam = (r - 4) >> 3, kk = (r - 4) & 7;
        int h = quad * 4 + (j & 3), i = 2 * kk + (j >> 2);
        if (m < KVO) v = w2n[((fam * 16 + h) * KVO + m) * 16 + i];
    } else {
        int kk = r - 28;
        int h = quad * 4 + (j & 3);
        int ifx = 2 * kk + (j >> 2);
        int i = ifx / 3, f = ifx % 3;
        if (m < KVO) v = w211[((h * KVO + m) * 16 + i) * 3 + f];
    }
    Wfrag[t] = __half_as_ushort(__float2half(v));
}

// ---------------- fused MFMA conv (+H, +z), f16 operands ----------------
// vrow[pos][32]: [0..8) scalar d | [8..32) 8+d*3+m.  zb[pos][4]: per-head z.
template <int KVO, bool DO_Z>
__global__ __launch_bounds__(256) void k_conv(
    int E,
    const int* __restrict__ src, const int* __restrict__ dst,
    const int* __restrict__ pose,
    const float* __restrict__ xs0, const float* __restrict__ xs1,
    const float* __restrict__ b00, const float* __restrict__ b01,
    const float* __restrict__ b10, const float* __restrict__ b11,
    const unsigned short* __restrict__ efh,    // (E,16) f16
    const unsigned short* __restrict__ Wfrag,  // frag-ordered weights (f16)
    int wbase,                                 // frag-row base for this conv
    const float* __restrict__ q0, const float* __restrict__ q1,
    float* __restrict__ vrow, float* __restrict__ zb)
{
    __shared__ unsigned xBL[4][16 * 148];  // per-wave: [m][p*48+if], dup-half2
    int tid = threadIdx.x;
    int wave = tid >> 6, lane = tid & 63;
    int tile = blockIdx.x * 4 + wave;
    if (tile * 16 >= E) return;
    int m = lane & 15, quad = lane >> 4;
    int e0 = tile * 16;
    int me = e0 + m;
    int s = src[me];
    unsigned* xw = xBL[wave];
    const half8* W8 = (const half8*)Wfrag;

    // ---- xB[p][if] = sum_q x1[i][q]*b11[p][q][f]; quad covers i in [quad*4,+4) ----
    {
        float x1c[12];
        const float4* xp = (const float4*)(xs1 + (size_t)s * 48 + quad * 12);
#pragma unroll
        for (int cc = 0; cc < 3; ++cc) {
            float4 v = xp[cc];
            x1c[cc * 4 + 0] = v.x; x1c[cc * 4 + 1] = v.y;
            x1c[cc * 4 + 2] = v.z; x1c[cc * 4 + 3] = v.w;
        }
        float b11r[27];
#pragma unroll
        for (int k = 0; k < 27; ++k) b11r[k] = b11[(size_t)me * 27 + k];
#pragma unroll
        for (int p = 0; p < 3; ++p) {
            float vals[12];
#pragma unroll
            for (int i2 = 0; i2 < 4; ++i2) {
#pragma unroll
                for (int f = 0; f < 3; ++f) {
                    float a = 0.f;
#pragma unroll
                    for (int q = 0; q < 3; ++q) a += x1c[i2 * 3 + q] * b11r[p * 9 + q * 3 + f];
                    vals[i2 * 3 + f] = a;
                }
            }
#pragma unroll
            for (int cc = 0; cc < 3; ++cc) {
                unsigned uu[4];
#pragma unroll
                for (int i3 = 0; i3 < 4; ++i3) {
                    U32h2 u;
                    u.h = __float2half2_rn(vals[cc * 4 + i3]);
                    uu[i3] = u.u;
                }
                *(uint4*)&xw[m * 148 + p * 48 + quad * 12 + cc * 4] =
                    make_uint4(uu[0], uu[1], uu[2], uu[3]);
            }
        }
    }
    __syncthreads();

    // ---- x0 row and t10 row as duplicated half2 ----
    __half2 x0d[16], t10d[16];
    {
        const float4* p = (const float4*)(xs0 + (size_t)s * 16);
#pragma unroll
        for (int k = 0; k < 4; ++k) {
            float4 v = p[k];
            x0d[k * 4 + 0] = __float2half2_rn(v.x);
            x0d[k * 4 + 1] = __float2half2_rn(v.y);
            x0d[k * 4 + 2] = __float2half2_rn(v.z);
            x0d[k * 4 + 3] = __float2half2_rn(v.w);
        }
        float bq0 = b10[(size_t)me * 3 + 0], bq1 = b10[(size_t)me * 3 + 1],
              bq2 = b10[(size_t)me * 3 + 2];
        const float4* xp = (const float4*)(xs1 + (size_t)s * 48);
#pragma unroll
        for (int g = 0; g < 4; ++g) {
            float4 a = xp[g * 3 + 0], b = xp[g * 3 + 1], cc = xp[g * 3 + 2];
            float xf[12] = {a.x, a.y, a.z, a.w, b.x, b.y, b.z, b.w, cc.x, cc.y, cc.z, cc.w};
#pragma unroll
            for (int i2 = 0; i2 < 4; ++i2)
                t10d[g * 4 + i2] = __float2half2_rn(
                    bq0 * xf[i2 * 3] + bq1 * xf[i2 * 3 + 1] + bq2 * xf[i2 * 3 + 2]);
        }
    }

    // ---- H via 4 f16 MFMAs: C[row=h=quad*4+r][col=edge=m]; packed as half2 ----
    __half2 Hp2[4][2];
    {
        half8 efr = {0, 0, 0, 0, 0, 0, 0, 0};
        if (quad < 2) efr = *(const half8*)(efh + (size_t)me * 16 + quad * 8);
        f32x4 z4 = {0.f, 0.f, 0.f, 0.f};
#pragma unroll
        for (int pp = 0; pp < 4; ++pp) {
            half8 w1f = W8[(size_t)(wbase + pp) * 64 + lane];
            f32x4 hacc = __builtin_amdgcn_mfma_f32_16x16x32_f16(w1f, efr, z4, 0, 0, 0);
            Hp2[pp][0] = __float22half2_rn(
                make_float2(fmaxf(hacc[0], 0.f), fmaxf(hacc[1], 0.f)));
            Hp2[pp][1] = __float22half2_rn(
                make_float2(fmaxf(hacc[2], 0.f), fmaxf(hacc[3], 0.f)));
        }
    }

    f32x4 acc0 = {0.f, 0.f, 0.f, 0.f}, acc1 = acc0, acc2 = acc0;
    f32x4 accP0 = acc0, accP1 = acc0, accP2 = acc0;

    // ---- loop1: fams 0,1,2 (K=256) ----
#pragma unroll
    for (int kk = 0; kk < 8; ++kk) {
        __half2 xA = x0d[2 * kk], xB = x0d[2 * kk + 1];
        __half2 tA = t10d[2 * kk], tB = t10d[2 * kk + 1];
        AF a0, a1, a2;
        a0.h2[0] = __hmul2(Hp2[0][0], xA); a0.h2[1] = __hmul2(Hp2[0][1], xA);
        a0.h2[2] = __hmul2(Hp2[0][0], xB); a0.h2[3] = __hmul2(Hp2[0][1], xB);
        a1.h2[0] = __hmul2(Hp2[1][0], xA); a1.h2[1] = __hmul2(Hp2[1][1], xA);
        a1.h2[2] = __hmul2(Hp2[1][0], xB); a1.h2[3] = __hmul2(Hp2[1][1], xB);
        a2.h2[0] = __hmul2(Hp2[2][0], tA); a2.h2[1] = __hmul2(Hp2[2][1], tA);
        a2.h2[2] = __hmul2(Hp2[2][0], tB); a2.h2[3] = __hmul2(Hp2[2][1], tB);
        half8 w0 = W8[(size_t)(wbase + 4 + kk) * 64 + lane];
        half8 w1f = W8[(size_t)(wbase + 12 + kk) * 64 + lane];
        half8 w2f = W8[(size_t)(wbase + 20 + kk) * 64 + lane];
        acc0 = __builtin_amdgcn_mfma_f32_16x16x32_f16(w0, a0.h8, acc0, 0, 0, 0);
        acc1 = __builtin_amdgcn_mfma_f32_16x16x32_f16(w1f, a1.h8, acc1, 0, 0, 0);
        acc2 = __builtin_amdgcn_mfma_f32_16x16x32_f16(w2f, a2.h8, acc2, 0, 0, 0);
    }

    // ---- loop2: fam3 (K=768), 3 p-GEMMs share the W frag ----
#pragma unroll
    for (int kko = 0; kko < 12; ++kko) {
        uint4 xu0 = *(const uint4*)&xw[m * 148 + 0 * 48 + 4 * kko];
        uint4 xu1 = *(const uint4*)&xw[m * 148 + 1 * 48 + 4 * kko];
        uint4 xu2 = *(const uint4*)&xw[m * 148 + 2 * 48 + 4 * kko];
        unsigned qa0[4] = {xu0.x, xu0.y, xu0.z, xu0.w};
        unsigned qa1[4] = {xu1.x, xu1.y, xu1.z, xu1.w};
        unsigned qa2[4] = {xu2.x, xu2.y, xu2.z, xu2.w};
#pragma unroll
        for (int t = 0; t < 2; ++t) {
            U32h2 u;
            __half2 p0a, p0b, p1a, p1b, p2a, p2b;
            u.u = qa0[2 * t]; p0a = u.h; u.u = qa0[2 * t + 1]; p0b = u.h;
            u.u = qa1[2 * t]; p1a = u.h; u.u = qa1[2 * t + 1]; p1b = u.h;
            u.u = qa2[2 * t]; p2a = u.h; u.u = qa2[2 * t + 1]; p2b = u.h;
            AF a0, a1, a2;
            a0.h2[0] = __hmul2(Hp2[3][0], p0a); a0.h2[1] = __hmul2(Hp2[3][1], p0a);
            a0.h2[2] = __hmul2(Hp2[3][0], p0b); a0.h2[3] = __hmul2(Hp2[3][1], p0b);
            a1.h2[0] = __hmul2(Hp2[3][0], p1a); a1.h2[1] = __hmul2(Hp2[3][1], p1a);
            a1.h2[2] = __hmul2(Hp2[3][0], p1b); a1.h2[3] = __hmul2(Hp2[3][1], p1b);
            a2.h2[0] = __hmul2(Hp2[3][0], p2a); a2.h2[1] = __hmul2(Hp2[3][1], p2a);
            a2.h2[2] = __hmul2(Hp2[3][0], p2b); a2.h2[3] = __hmul2(Hp2[3][1], p2b);
            half8 wf = W8[(size_t)(wbase + 28 + 2 * kko + t) * 64 + lane];
            accP0 = __builtin_amdgcn_mfma_f32_16x16x32_f16(wf, a0.h8, accP0, 0, 0, 0);
            accP1 = __builtin_amdgcn_mfma_f32_16x16x32_f16(wf, a1.h8, accP1, 0, 0, 0);
            accP2 = __builtin_amdgcn_mfma_f32_16x16x32_f16(wf, a2.h8, accP2, 0, 0, 0);
        }
    }

    // ---- epilogue: lane holds oo = quad*4+r for edge me ----
    float b00r = b00[me];
    float b01r0 = b01[(size_t)me * 3 + 0], b01r1 = b01[(size_t)me * 3 + 1],
          b01r2 = b01[(size_t)me * 3 + 2];
    float o0v[4], o1v[4][3];
#pragma unroll
    for (int r = 0; r < 4; ++r) {
        o0v[r] = b00r * acc0[r] + acc2[r];
        o1v[r][0] = b01r0 * acc1[r] + accP0[r];
        o1v[r][1] = b01r1 * acc1[r] + accP1[r];
        o1v[r][2] = b01r2 * acc1[r] + accP2[r];
    }
    int pos = pose[me];
    bool doStore = DO_Z ? (quad >= 2) : (quad < 2);
    if (doStore) {
        int qa = DO_Z ? (quad - 2) : quad;
        float* vp = vrow + (size_t)pos * 32;
        *(float4*)&vp[qa * 4] = make_float4(o0v[0], o0v[1], o0v[2], o0v[3]);
        float* p1 = vp + 8 + qa * 12;
        *(float4*)&p1[0] = make_float4(o1v[0][0], o1v[0][1], o1v[0][2], o1v[1][0]);
        *(float4*)&p1[4] = make_float4(o1v[1][1], o1v[1][2], o1v[2][0], o1v[2][1]);
        *(float4*)&p1[8] = make_float4(o1v[2][2], o1v[3][0], o1v[3][1], o1v[3][2]);
    }
    if (DO_Z && quad < 2) {
        int n = dst[me];
        float4 q0v = *(const float4*)&q0[(size_t)n * 8 + quad * 4];
        const float4* q1p = (const float4*)&q1[(size_t)n * 24 + quad * 12];
        float4 qa4 = q1p[0], qb4 = q1p[1], qc4 = q1p[2];
        float q1f[12] = {qa4.x, qa4.y, qa4.z, qa4.w, qb4.x, qb4.y, qb4.z, qb4.w,
                         qc4.x, qc4.y, qc4.z, qc4.w};
        float q0f[4] = {q0v.x, q0v.y, q0v.z, q0v.w};
        float zh0 = 0.f, zh1 = 0.f;
#pragma unroll
        for (int r = 0; r < 4; ++r) {
            float tt = q0f[r] * o0v[r] + q1f[r * 3 + 0] * o1v[r][0] +
                       q1f[r * 3 + 1] * o1v[r][1] + q1f[r * 3 + 2] * o1v[r][2];
            if (r < 2) zh0 += tt;
            else zh1 += tt;
        }
        const float scale = 0.35355339059327373f;  // 1/sqrt(8)
        *(float2*)&zb[(size_t)pos * 4 + quad * 2] = make_float2(zh0 * scale, zh1 * scale);
    }
}

// ---------------- q projection ----------------
__global__ void k_q(int N, const float* __restrict__ xs0, const float* __restrict__ xs1,
                    const float* __restrict__ wq,
                    float* __restrict__ q0, float* __restrict__ q1) {
    int t = blockIdx.x * 256 + threadIdx.x;
    if (t >= N * 32) return;
    int n = t >> 5, comp = t & 31;
    if (comp < 8) {
        float a = 0.f;
#pragma unroll
        for (int c = 0; c < 16; ++c) a += xs0[n * 16 + c] * wq[c * 8 + comp];
        q0[n * 8 + comp] = a;
    } else {
        int idx = comp - 8, dd = idx / 3, mm = idx % 3;
        float a = 0.f;
#pragma unroll
        for (int c = 0; c < 16; ++c) a += xs1[n * 48 + c * 3 + mm] * wq[128 + c * 8 + dd];
        q1[n * 24 + dd * 3 + mm] = a;
    }
}

// ---------------- per-node: softmax + aggregate + proj + SE3-norm ----------------
// 4 nodes per wave, 16 lanes per node; 16 nodes per block. CSR-ordered reads.
__global__ __launch_bounds__(256) void k_attn(
    int N,
    const int* __restrict__ rowptr,
    const float* __restrict__ zb, const float* __restrict__ vrow,
    const float* __restrict__ wproj,  // (2,24,16)
    const float* __restrict__ gamma, const float* __restrict__ beta,  // (2,16)
    float* __restrict__ xs0, float* __restrict__ xs1) {
    __shared__ float wpL[768];
    __shared__ float gL[32], btL[32];
    __shared__ float inb[16][100];   // per node: in0[24] + in1[72]
    __shared__ float aw[16][16][4];  // per node: alpha chunk
    int tid = threadIdx.x;
    for (int i = tid; i < 768; i += 256) wpL[i] = wproj[i];
    if (tid < 32) { gL[tid] = gamma[tid]; btL[tid] = beta[tid]; }
    int wave = tid >> 6, lane = tid & 63;
    int sub = lane >> 4, l16 = lane & 15;
    int nodeIdx = wave * 4 + sub;
    int n = blockIdx.x * 16 + nodeIdx;
    if (n >= N) n = N - 1;
    int base = rowptr[n], deg = rowptr[n + 1] - base;
    const float4* zb4 = (const float4*)zb;

    // pass 1: per-head max (coalesced)
    float mx0 = -INFINITY, mx1 = -INFINITY, mx2 = -INFINITY, mx3 = -INFINITY;
    for (int j = l16; j < deg; j += 16) {
        float4 zv = zb4[base + j];
        mx0 = fmaxf(mx0, zv.x); mx1 = fmaxf(mx1, zv.y);
        mx2 = fmaxf(mx2, zv.z); mx3 = fmaxf(mx3, zv.w);
    }
#pragma unroll
    for (int off = 1; off < 16; off <<= 1) {
        mx0 = fmaxf(mx0, __shfl_xor(mx0, off));
        mx1 = fmaxf(mx1, __shfl_xor(mx1, off));
        mx2 = fmaxf(mx2, __shfl_xor(mx2, off));
        mx3 = fmaxf(mx3, __shfl_xor(mx3, off));
    }
    if (!isfinite(mx0)) mx0 = 0.f;
    if (!isfinite(mx1)) mx1 = 0.f;
    if (!isfinite(mx2)) mx2 = 0.f;
    if (!isfinite(mx3)) mx3 = 0.f;

    // pass 2: per-head sum
    float s0 = 0.f, s1 = 0.f, s2 = 0.f, s3 = 0.f;
    for (int j = l16; j < deg; j += 16) {
        float4 zv = zb4[base + j];
        s0 += __expf(zv.x - mx0); s1 += __expf(zv.y - mx1);
        s2 += __expf(zv.z - mx2); s3 += __expf(zv.w - mx3);
    }
#pragma unroll
    for (int off = 1; off < 16; off <<= 1) {
        s0 += __shfl_xor(s0, off); s1 += __shfl_xor(s1, off);
        s2 += __shfl_xor(s2, off); s3 += __shfl_xor(s3, off);
    }
    float i0 = 1.f / (s0 + 1e-9f), i1 = 1.f / (s1 + 1e-9f);
    float i2 = 1.f / (s2 + 1e-9f), i3 = 1.f / (s3 + 1e-9f);

    // pass 3: chunked alpha -> LDS, accumulate two comps per lane
    int c0 = 2 * l16, c1 = c0 + 1;
    int hA = ((c0 < 8) ? c0 : (c0 - 8) / 3) >> 1;
    int hB = ((c1 < 8) ? c1 : (c1 - 8) / 3) >> 1;
    float accA = 0.f, accB = 0.f;
    for (int j0 = 0; j0 < deg; j0 += 16) {
        int j = j0 + l16;
        float4 a4 = make_float4(0.f, 0.f, 0.f, 0.f);
        if (j < deg) {
            float4 zv = zb4[base + j];
            a4.x = __expf(zv.x - mx0) * i0;
            a4.y = __expf(zv.y - mx1) * i1;
            a4.z = __expf(zv.z - mx2) * i2;
            a4.w = __expf(zv.w - mx3) * i3;
        }
        *(float4*)&aw[nodeIdx][l16][0] = a4;
        __builtin_amdgcn_wave_barrier();
        int cnt = min(16, deg - j0);
        for (int jj = 0; jj < cnt; ++jj) {
            float2 v = *(const float2*)&vrow[(size_t)(base + j0 + jj) * 32 + c0];
            accA += aw[nodeIdx][jj][hA] * v.x;
            accB += aw[nodeIdx][jj][hB] * v.y;
        }
        __builtin_amdgcn_wave_barrier();
    }

    // stage concat([o, x]) into LDS
    float* in0 = inb[nodeIdx];
    float* in1 = in0 + 24;
    if (c0 < 8) { in0[c0] = accA; in0[c1] = accB; }
    else        { in1[c0 - 8] = accA; in1[c1 - 8] = accB; }
    in0[8 + l16] = xs0[(size_t)n * 16 + l16];
    {
        const float* xp = xs1 + (size_t)n * 48 + l16 * 3;
        in1[24 + l16 * 3 + 0] = xp[0];
        in1[24 + l16 * 3 + 1] = xp[1];
        in1[24 + l16 * 3 + 2] = xp[2];
    }
    __syncthreads();

    // projection: each lane -> 4 outputs of its node (1 scalar + 3 vector comps)
    int c = l16;
    float y0 = 0.f;
#pragma unroll
    for (int j = 0; j < 24; ++j) y0 += in0[j] * wpL[j * 16 + c];
    float y1v[3];
#pragma unroll
    for (int mm = 0; mm < 3; ++mm) {
        float y = 0.f;
#pragma unroll
        for (int j = 0; j < 24; ++j) y += in1[j * 3 + mm] * wpL[384 + j * 16 + c];
        y1v[mm] = y;
    }
    float n0 = sqrtf(y0 * y0 + 1e-12f);
    float n1 = sqrtf(y1v[0] * y1v[0] + y1v[1] * y1v[1] + y1v[2] * y1v[2] + 1e-12f);
    float mu0 = n0, mu1 = n1;
#pragma unroll
    for (int off = 1; off < 16; off <<= 1) {
        mu0 += __shfl_xor(mu0, off);
        mu1 += __shfl_xor(mu1, off);
    }
    mu0 *= 0.0625f; mu1 *= 0.0625f;
    float dv0 = n0 - mu0, dv1 = n1 - mu1;
    float var0 = dv0 * dv0, var1 = dv1 * dv1;
#pragma unroll
    for (int off = 1; off < 16; off <<= 1) {
        var0 += __shfl_xor(var0, off);
        var1 += __shfl_xor(var1, off);
    }
    var0 *= 0.0625f; var1 *= 0.0625f;
    float ln0 = dv0 * rsqrtf(var0 + 1e-5f) * gL[c] + btL[c];
    float ln1 = dv1 * rsqrtf(var1 + 1e-5f) * gL[16 + c] + btL[16 + c];
    float fac0 = fmaxf(ln0, 0.f) / (n0 + 1e-3f);
    float fac1 = fmaxf(ln1, 0.f) / (n1 + 1e-3f);
    xs0[(size_t)n * 16 + c] = y0 * fac0;
    float* xo = xs1 + (size_t)n * 48 + c * 3;
    xo[0] = y1v[0] * fac1;
    xo[1] = y1v[1] * fac1;
    xo[2] = y1v[2] * fac1;
}

// ---------------- final output: segment-sum(vrow) + x @ wself ----------------
__global__ __launch_bounds__(256) void k_out(
    int N,
    const int* __restrict__ rowptr, const float* __restrict__ vrow,
    const float* __restrict__ xs0, const float* __restrict__ xs1,
    const float* __restrict__ wself,  // (2,16,8)
    float* __restrict__ out) {
    int tid = threadIdx.x;
    int wave = tid >> 6, lane = tid & 63;
    int sub = lane >> 4, l16 = lane & 15;
    int n = blockIdx.x * 16 + wave * 4 + sub;
    if (n >= N) n = N - 1;
    int base = rowptr[n], deg = rowptr[n + 1] - base;

    int c0 = 2 * l16, c1 = c0 + 1;
    float accA = 0.f, accB = 0.f;
    for (int j = 0; j < deg; ++j) {
        float2 v = *(const float2*)&vrow[(size_t)(base + j) * 32 + c0];
        accA += v.x;
        accB += v.y;
    }
    if (c0 < 8) {
#pragma unroll
        for (int c = 0; c < 16; ++c) {
            float xv = xs0[(size_t)n * 16 + c];
            accA += xv * wself[c * 8 + c0];
            accB += xv * wself[c * 8 + c1];
        }
    } else {
        int dA = (c0 - 8) / 3, mA = (c0 - 8) % 3;
        int dB = (c1 - 8) / 3, mB = (c1 - 8) % 3;
#pragma unroll
        for (int c = 0; c < 16; ++c) {
            accA += xs1[(size_t)n * 48 + c * 3 + mA] * wself[128 + c * 8 + dA];
            accB += xs1[(size_t)n * 48 + c * 3 + mB] * wself[128 + c * 8 + dB];
        }
    }
    *(float2*)&out[(size_t)n * 32 + c0] = make_float2(accA, accB);
}

// ---------------------------------------------------------------------------
extern "C" void kernel_launch(void* const* d_in, const int* in_sizes, int n_in,
                              void* d_out, int out_size, void* d_ws, size_t ws_size,
                              hipStream_t stream) {
    const float* x0 = (const float*)d_in[0];
    const float* x1 = (const float*)d_in[1];
    const float* ef = (const float*)d_in[2];
    const float* b00 = (const float*)d_in[3];
    const float* b01 = (const float*)d_in[4];
    const float* b10 = (const float*)d_in[5];
    const float* b11 = (const float*)d_in[6];
    const float* kvw1 = (const float*)d_in[7];    // (2,4,16,16)
    const float* kvw2n = (const float*)d_in[8];   // (2,3,16,16,16)
    const float* kvw211 = (const float*)d_in[9];  // (2,16,16,16,3)
    const float* wq = (const float*)d_in[10];     // (2,2,16,8)
    const float* wproj = (const float*)d_in[11];  // (2,2,24,16)
    const float* gam = (const float*)d_in[12];    // (2,2,16)
    const float* bet = (const float*)d_in[13];
    const float* fcw1 = (const float*)d_in[14];    // (4,16,16)
    const float* fcw2n = (const float*)d_in[15];   // (3,16,8,16)
    const float* fcw211 = (const float*)d_in[16];  // (16,8,16,3)
    const float* fcself = (const float*)d_in[17];  // (2,16,8)
    const int* esrc = (const int*)d_in[18];
    const int* edst = (const int*)d_in[19];
    int N = in_sizes[0] / 16;
    int E = in_sizes[18];
    float* out = (float*)d_out;

    float* ws = (float*)d_ws;
    size_t off = 0;
    float* xs0 = ws + off; off += (size_t)N * 16;
    float* xs1 = ws + off; off += (size_t)N * 48;
    float* q0b = ws + off; off += (size_t)N * 8;
    float* q1b = ws + off; off += (size_t)N * 24;
    float* vrow = ws + off; off += (size_t)E * 32;
    float* zb = ws + off; off += (size_t)E * 4;
    int* counts = (int*)(ws + off); off += N;
    int* rowptr = (int*)(ws + off); off += N + 1;
    int* cursor = (int*)(ws + off); off += N;
    int* pose = (int*)(ws + off); off += E;
    off = (off + 3) & ~(size_t)3;
    unsigned short* efh = (unsigned short*)(ws + off); off += (size_t)E * 16 / 2;
    unsigned short* Wfrag = (unsigned short*)(ws + off); off += (size_t)156 * 64 * 8 / 2;

    const int tpb = 256;
    int ebl = (E + 255) / 256;
    int cblk = (E / 16 + 3) / 4;
    int nbl16 = (N + 15) / 16;

    k_prepw<<<(156 * 512 + 255) / 256, tpb, 0, stream>>>(kvw1, fcw1, kvw2n, kvw211,
                                                         fcw2n, fcw211, Wfrag);
    int mtot = N * 64 + E * 16;
    k_misc<<<(mtot + 255) / 256, tpb, 0, stream>>>(x0, x1, ef, xs0, xs1, efh,
                                                   N * 16, N * 48, E * 16);
    hipMemsetAsync(counts, 0, (size_t)N * 4, stream);
    k_hist<<<ebl, tpb, 0, stream>>>(edst, counts, E);
    int CH = (N + 1023) / 1024;
    k_scan<<<1, 1024, 0, stream>>>(counts, rowptr, cursor, N, CH);
    k_scatter<<<ebl, tpb, 0, stream>>>(edst, cursor, pose, E);

    for (int l = 0; l < 2; ++l) {
        k_q<<<(N * 32 + 255) / 256, tpb, 0, stream>>>(N, xs0, xs1, wq + l * 256, q0b, q1b);
        k_conv<16, true><<<cblk, tpb, 0, stream>>>(E, esrc, edst, pose, xs0, xs1,
                                                   b00, b01, b10, b11, efh, Wfrag, l * 52,
                                                   q0b, q1b, vrow, zb);
        k_attn<<<nbl16, tpb, 0, stream>>>(N, rowptr, zb, vrow, wproj + l * 768,
                                          gam + l * 32, bet + l * 32, xs0, xs1);
    }
    k_conv<8, false><<<cblk, tpb, 0, stream>>>(E, esrc, edst, pose, xs0, xs1,
                                               b00, b01, b10, b11, efh, Wfrag, 2 * 52,
                                               q0b, q1b, vrow, zb);
    k_out<<<nbl16, tpb, 0, stream>>>(N, rowptr, vrow, xs0, xs1, fcself, out);
}

// Round 7
// 292.911 us; speedup vs baseline: 7.0508x; 1.0077x over previous
//
#include <hip/hip_runtime.h>
#include <hip/hip_fp16.h>
#include <math.h>

// ---------------------------------------------------------------------------
// EquivariantNet forward — round 7.
// r6 + (1) pair-shared-H k-mapping: A-pairs = dup(H) * natural x-half2-pairs,
// halving xB LDS (37888->18944B) and x register count, (2) k_attn alpha-v
// accumulation unrolled x4 + next-layer q fused into k_attn epilogue,
// (3) k_out unrolled x4.
// k-mapping (all fams): h = quad*4 + ((j>>1)&3), i/if = 2kk + (j&1).
// Shapes: N=8192, E=131072, C=16, mid=16, KV=16, ckv=8, Co=8, HEADS=4, L=2
// ---------------------------------------------------------------------------

typedef _Float16 half8 __attribute__((ext_vector_type(8)));
typedef float f32x4 __attribute__((ext_vector_type(4)));

union AF {
    half8 h8;
    __half2 h2[4];
};
union U32h2 {
    unsigned u;
    __half2 h;
};

// ---------------- CSR build over edge_dst ----------------
__global__ void k_hist(const int* __restrict__ dst, int* __restrict__ counts, int E) {
    int e = blockIdx.x * 256 + threadIdx.x;
    if (e < E) atomicAdd(&counts[dst[e]], 1);
}

__global__ __launch_bounds__(1024) void k_scan(const int* __restrict__ counts,
                                               int* __restrict__ rowptr,
                                               int* __restrict__ cursor,
                                               int N, int CH) {
    __shared__ int part[1024];
    int t = threadIdx.x;
    int s = 0;
    for (int i = 0; i < CH; ++i) {
        int idx = t * CH + i;
        if (idx < N) s += counts[idx];
    }
    part[t] = s;
    __syncthreads();
    for (int off = 1; off < 1024; off <<= 1) {
        int v = (t >= off) ? part[t - off] : 0;
        __syncthreads();
        part[t] += v;
        __syncthreads();
    }
    int run = (t == 0) ? 0 : part[t - 1];
    for (int i = 0; i < CH; ++i) {
        int idx = t * CH + i;
        if (idx < N) {
            rowptr[idx] = run;
            cursor[idx] = run;
            run += counts[idx];
        }
    }
    if (t == 0) rowptr[N] = part[1023];
}

__global__ void k_scatter(const int* __restrict__ dst, int* __restrict__ cursor,
                          int* __restrict__ pose, int E) {
    int e = blockIdx.x * 256 + threadIdx.x;
    if (e < E) {
        int pos = atomicAdd(&cursor[dst[e]], 1);
        pose[e] = pos;
    }
}

// ---------------- fused init: xs copies + ef->f16 ----------------
__global__ void k_misc(const float* __restrict__ x0, const float* __restrict__ x1,
                       const float* __restrict__ ef,
                       float* __restrict__ xs0, float* __restrict__ xs1,
                       unsigned short* __restrict__ efh, int n0, int n1, int n2) {
    int i = blockIdx.x * 256 + threadIdx.x;
    if (i < n0) xs0[i] = x0[i];
    else if (i < n0 + n1) xs1[i - n0] = x1[i - n0];
    else if (i < n0 + n1 + n2) {
        int k = i - n0 - n1;
        efh[k] = __half_as_ushort(__float2half(ef[k]));
    }
}

// ---------------- weight permute into A-fragment order (f16) ----------------
// 52 frag-rows per conv (conv c base = c*52):
//   rows 0..3   : w1 A-frags, A[m=h][k=f]: w1[pp][f=quad*8+j][h=m], quad<2 else 0
//   rows 4..27  : fams 0..2 (fam*8+kk): h = quad*4+((j>>1)&3), i = 2kk+(j&1)
//   rows 28..51 : fam 3 (kk2 0..23):    h = quad*4+((j>>1)&3), if = 2kk2+(j&1)
__global__ void k_prepw(const float* __restrict__ kvw1, const float* __restrict__ fcw1,
                        const float* __restrict__ kvw2n, const float* __restrict__ kvw211,
                        const float* __restrict__ fcw2n, const float* __restrict__ fcw211,
                        unsigned short* __restrict__ Wfrag) {
    int t = blockIdx.x * 256 + threadIdx.x;
    if (t >= 156 * 64 * 8) return;
    int j = t & 7;
    int lane = (t >> 3) & 63;
    int row = t >> 9;
    int quad = lane >> 4, m = lane & 15;
    int c = row / 52, r = row % 52;
    int KVO = (c < 2) ? 16 : 8;
    const float* w1src = (c < 2) ? (kvw1 + c * 1024) : fcw1;
    const float* w2n = (c < 2) ? (kvw2n + c * 12288) : fcw2n;
    const float* w211 = (c < 2) ? (kvw211 + c * 12288) : fcw211;
    float v = 0.f;
    if (r < 4) {
        if (quad < 2) v = w1src[r * 256 + (quad * 8 + j) * 16 + m];
    } else if (r < 28) {
        int fam = (r - 4) >> 3, kk = (r - 4) & 7;
        int h = quad * 4 + ((j >> 1) & 3), i = 2 * kk + (j & 1);
        if (m < KVO) v = w2n[((fam * 16 + h) * KVO + m) * 16 + i];
    } else {
        int kk2 = r - 28;
        int h = quad * 4 + ((j >> 1) & 3);
        int ifx = 2 * kk2 + (j & 1);
        int i = ifx / 3, f = ifx % 3;
        if (m < KVO) v = w211[((h * KVO + m) * 16 + i) * 3 + f];
    }
    Wfrag[t] = __half_as_ushort(__float2half(v));
}

// ---------------- fused MFMA conv (+H, +z), f16, pair-shared-H builds --------
// vrow[pos][32]: [0..8) scalar d | [8..32) 8+d*3+m.  zb[pos][4]: per-head z.
template <int KVO, bool DO_Z>
__global__ __launch_bounds__(256) void k_conv(
    int E,
    const int* __restrict__ src, const int* __restrict__ dst,
    const int* __restrict__ pose,
    const float* __restrict__ xs0, const float* __restrict__ xs1,
    const float* __restrict__ b00, const float* __restrict__ b01,
    const float* __restrict__ b10, const float* __restrict__ b11,
    const unsigned short* __restrict__ efh,    // (E,16) f16
    const unsigned short* __restrict__ Wfrag,  // frag-ordered weights (f16)
    int wbase,
    const float* __restrict__ q0, const float* __restrict__ q1,
    float* __restrict__ vrow, float* __restrict__ zb)
{
    // xB pairs: [wave][m][p*24 + u], u = if/2 (0..23), each uint = half2 pair
    __shared__ __align__(16) unsigned xBL[4][16 * 74];
    int tid = threadIdx.x;
    int wave = tid >> 6, lane = tid & 63;
    int tile = blockIdx.x * 4 + wave;
    if (tile * 16 >= E) return;
    int m = lane & 15, quad = lane >> 4;
    int e0 = tile * 16;
    int me = e0 + m;
    int s = src[me];
    unsigned* xw = xBL[wave];
    const half8* W8 = (const half8*)Wfrag;

    // ---- xB[p][if] = sum_q x1[i][q]*b11[p][q][f]; quad covers if [quad*12,+12) ----
    {
        float x1c[12];
        const float4* xp = (const float4*)(xs1 + (size_t)s * 48 + quad * 12);
#pragma unroll
        for (int cc = 0; cc < 3; ++cc) {
            float4 v = xp[cc];
            x1c[cc * 4 + 0] = v.x; x1c[cc * 4 + 1] = v.y;
            x1c[cc * 4 + 2] = v.z; x1c[cc * 4 + 3] = v.w;
        }
        float b11r[27];
#pragma unroll
        for (int k = 0; k < 27; ++k) b11r[k] = b11[(size_t)me * 27 + k];
#pragma unroll
        for (int p = 0; p < 3; ++p) {
            float vals[12];
#pragma unroll
            for (int i2 = 0; i2 < 4; ++i2) {
#pragma unroll
                for (int f = 0; f < 3; ++f) {
                    float a = 0.f;
#pragma unroll
                    for (int q = 0; q < 3; ++q) a += x1c[i2 * 3 + q] * b11r[p * 9 + q * 3 + f];
                    vals[i2 * 3 + f] = a;
                }
            }
            unsigned uu[6];
#pragma unroll
            for (int u = 0; u < 6; ++u) {
                U32h2 w;
                w.h = __float22half2_rn(make_float2(vals[2 * u], vals[2 * u + 1]));
                uu[u] = w.u;
            }
            int boff = m * 74 + p * 24 + quad * 6;
            *(uint2*)&xw[boff + 0] = make_uint2(uu[0], uu[1]);
            *(uint2*)&xw[boff + 2] = make_uint2(uu[2], uu[3]);
            *(uint2*)&xw[boff + 4] = make_uint2(uu[4], uu[5]);
        }
    }
    __syncthreads();

    // ---- x0 / t10 rows as natural half2 pairs (8 regs each) ----
    __half2 x0p[8], t10p[8];
    {
        const float4* p = (const float4*)(xs0 + (size_t)s * 16);
#pragma unroll
        for (int k = 0; k < 4; ++k) {
            float4 v = p[k];
            x0p[2 * k + 0] = __float22half2_rn(make_float2(v.x, v.y));
            x0p[2 * k + 1] = __float22half2_rn(make_float2(v.z, v.w));
        }
        float bq0 = b10[(size_t)me * 3 + 0], bq1 = b10[(size_t)me * 3 + 1],
              bq2 = b10[(size_t)me * 3 + 2];
        const float4* xp = (const float4*)(xs1 + (size_t)s * 48);
        float tf[16];
#pragma unroll
        for (int g = 0; g < 4; ++g) {
            float4 a = xp[g * 3 + 0], b = xp[g * 3 + 1], cc = xp[g * 3 + 2];
            float xf[12] = {a.x, a.y, a.z, a.w, b.x, b.y, b.z, b.w, cc.x, cc.y, cc.z, cc.w};
#pragma unroll
            for (int i2 = 0; i2 < 4; ++i2)
                tf[g * 4 + i2] = bq0 * xf[i2 * 3] + bq1 * xf[i2 * 3 + 1] + bq2 * xf[i2 * 3 + 2];
        }
#pragma unroll
        for (int k = 0; k < 8; ++k)
            t10p[k] = __float22half2_rn(make_float2(tf[2 * k], tf[2 * k + 1]));
    }

    // ---- H via 4 f16 MFMAs -> dup-half2 per (pp, t): H[pp][h=quad*4+t] ----
    __half2 Hd[4][4];
    {
        half8 efr = {0, 0, 0, 0, 0, 0, 0, 0};
        if (quad < 2) efr = *(const half8*)(efh + (size_t)me * 16 + quad * 8);
        f32x4 z4 = {0.f, 0.f, 0.f, 0.f};
#pragma unroll
        for (int pp = 0; pp < 4; ++pp) {
            half8 w1f = W8[(size_t)(wbase + pp) * 64 + lane];
            f32x4 hacc = __builtin_amdgcn_mfma_f32_16x16x32_f16(w1f, efr, z4, 0, 0, 0);
#pragma unroll
            for (int r = 0; r < 4; ++r)
                Hd[pp][r] = __float2half2_rn(__float2half(fmaxf(hacc[r], 0.f)));
        }
    }

    f32x4 acc0 = {0.f, 0.f, 0.f, 0.f}, acc1 = acc0, acc2 = acc0;
    f32x4 accP0 = acc0, accP1 = acc0, accP2 = acc0;

    // ---- loop1: fams 0,1,2 (K=256): A.h2[t] = Hd[pp][t] * (x[2kk],x[2kk+1]) ----
#pragma unroll
    for (int kk = 0; kk < 8; ++kk) {
        __half2 xp_ = x0p[kk], tp_ = t10p[kk];
        AF a0, a1, a2;
#pragma unroll
        for (int t = 0; t < 4; ++t) {
            a0.h2[t] = __hmul2(Hd[0][t], xp_);
            a1.h2[t] = __hmul2(Hd[1][t], xp_);
            a2.h2[t] = __hmul2(Hd[2][t], tp_);
        }
        half8 w0 = W8[(size_t)(wbase + 4 + kk) * 64 + lane];
        half8 w1f = W8[(size_t)(wbase + 12 + kk) * 64 + lane];
        half8 w2f = W8[(size_t)(wbase + 20 + kk) * 64 + lane];
        acc0 = __builtin_amdgcn_mfma_f32_16x16x32_f16(w0, a0.h8, acc0, 0, 0, 0);
        acc1 = __builtin_amdgcn_mfma_f32_16x16x32_f16(w1f, a1.h8, acc1, 0, 0, 0);
        acc2 = __builtin_amdgcn_mfma_f32_16x16x32_f16(w2f, a2.h8, acc2, 0, 0, 0);
    }

    // ---- loop2: fam3 (K=768), MFMA kk2=2kko+t covers if-pair u=kk2 ----
#pragma unroll
    for (int kko = 0; kko < 12; ++kko) {
        uint2 xu0 = *(const uint2*)&xw[m * 74 + 0 * 24 + 2 * kko];
        uint2 xu1 = *(const uint2*)&xw[m * 74 + 1 * 24 + 2 * kko];
        uint2 xu2 = *(const uint2*)&xw[m * 74 + 2 * 24 + 2 * kko];
        unsigned pv0[2] = {xu0.x, xu0.y};
        unsigned pv1[2] = {xu1.x, xu1.y};
        unsigned pv2[2] = {xu2.x, xu2.y};
#pragma unroll
        for (int t = 0; t < 2; ++t) {
            U32h2 u0, u1, u2;
            u0.u = pv0[t]; u1.u = pv1[t]; u2.u = pv2[t];
            AF a0, a1, a2;
#pragma unroll
            for (int r = 0; r < 4; ++r) {
                a0.h2[r] = __hmul2(Hd[3][r], u0.h);
                a1.h2[r] = __hmul2(Hd[3][r], u1.h);
                a2.h2[r] = __hmul2(Hd[3][r], u2.h);
            }
            half8 wf = W8[(size_t)(wbase + 28 + 2 * kko + t) * 64 + lane];
            accP0 = __builtin_amdgcn_mfma_f32_16x16x32_f16(wf, a0.h8, accP0, 0, 0, 0);
            accP1 = __builtin_amdgcn_mfma_f32_16x16x32_f16(wf, a1.h8, accP1, 0, 0, 0);
            accP2 = __builtin_amdgcn_mfma_f32_16x16x32_f16(wf, a2.h8, accP2, 0, 0, 0);
        }
    }

    // ---- epilogue: lane holds oo = quad*4+r for edge me ----
    float b00r = b00[me];
    float b01r0 = b01[(size_t)me * 3 + 0], b01r1 = b01[(size_t)me * 3 + 1],
          b01r2 = b01[(size_t)me * 3 + 2];
    float o0v[4], o1v[4][3];
#pragma unroll
    for (int r = 0; r < 4; ++r) {
        o0v[r] = b00r * acc0[r] + acc2[r];
        o1v[r][0] = b01r0 * acc1[r] + accP0[r];
        o1v[r][1] = b01r1 * acc1[r] + accP1[r];
        o1v[r][2] = b01r2 * acc1[r] + accP2[r];
    }
    int pos = pose[me];
    bool doStore = DO_Z ? (quad >= 2) : (quad < 2);
    if (doStore) {
        int qa = DO_Z ? (quad - 2) : quad;
        float* vp = vrow + (size_t)pos * 32;
        *(float4*)&vp[qa * 4] = make_float4(o0v[0], o0v[1], o0v[2], o0v[3]);
        float* p1 = vp + 8 + qa * 12;
        *(float4*)&p1[0] = make_float4(o1v[0][0], o1v[0][1], o1v[0][2], o1v[1][0]);
        *(float4*)&p1[4] = make_float4(o1v[1][1], o1v[1][2], o1v[2][0], o1v[2][1]);
        *(float4*)&p1[8] = make_float4(o1v[2][2], o1v[3][0], o1v[3][1], o1v[3][2]);
    }
    if (DO_Z && quad < 2) {
        int n = dst[me];
        float4 q0v = *(const float4*)&q0[(size_t)n * 8 + quad * 4];
        const float4* q1p = (const float4*)&q1[(size_t)n * 24 + quad * 12];
        float4 qa4 = q1p[0], qb4 = q1p[1], qc4 = q1p[2];
        float q1f[12] = {qa4.x, qa4.y, qa4.z, qa4.w, qb4.x, qb4.y, qb4.z, qb4.w,
                         qc4.x, qc4.y, qc4.z, qc4.w};
        float q0f[4] = {q0v.x, q0v.y, q0v.z, q0v.w};
        float zh0 = 0.f, zh1 = 0.f;
#pragma unroll
        for (int r = 0; r < 4; ++r) {
            float tt = q0f[r] * o0v[r] + q1f[r * 3 + 0] * o1v[r][0] +
                       q1f[r * 3 + 1] * o1v[r][1] + q1f[r * 3 + 2] * o1v[r][2];
            if (r < 2) zh0 += tt;
            else zh1 += tt;
        }
        const float scale = 0.35355339059327373f;  // 1/sqrt(8)
        *(float2*)&zb[(size_t)pos * 4 + quad * 2] = make_float2(zh0 * scale, zh1 * scale);
    }
}

// ---------------- q projection (layer 0 only) ----------------
__global__ void k_q(int N, const float* __restrict__ xs0, const float* __restrict__ xs1,
                    const float* __restrict__ wq,
                    float* __restrict__ q0, float* __restrict__ q1) {
    int t = blockIdx.x * 256 + threadIdx.x;
    if (t >= N * 32) return;
    int n = t >> 5, comp = t & 31;
    if (comp < 8) {
        float a = 0.f;
#pragma unroll
        for (int c = 0; c < 16; ++c) a += xs0[n * 16 + c] * wq[c * 8 + comp];
        q0[n * 8 + comp] = a;
    } else {
        int idx = comp - 8, dd = idx / 3, mm = idx % 3;
        float a = 0.f;
#pragma unroll
        for (int c = 0; c < 16; ++c) a += xs1[n * 48 + c * 3 + mm] * wq[128 + c * 8 + dd];
        q1[n * 24 + dd * 3 + mm] = a;
    }
}

// ---------------- per-node: softmax + aggregate + proj + SE3-norm (+next q) --
// 4 nodes per wave, 16 lanes per node; 16 nodes per block. CSR-ordered reads.
__global__ __launch_bounds__(256) void k_attn(
    int N,
    const int* __restrict__ rowptr,
    const float* __restrict__ zb, const float* __restrict__ vrow,
    const float* __restrict__ wproj,  // (2,24,16)
    const float* __restrict__ gamma, const float* __restrict__ beta,  // (2,16)
    float* __restrict__ xs0, float* __restrict__ xs1,
    const float* __restrict__ wq_next,  // next layer wq (2,16,8) or nullptr
    float* __restrict__ q0, float* __restrict__ q1) {
    __shared__ float wpL[768];
    __shared__ float gL[32], btL[32];
    __shared__ float inb[16][100];   // per node: in0[24] + in1[72]
    __shared__ float aw[16][16][4];  // per node: alpha chunk
    int tid = threadIdx.x;
    for (int i = tid; i < 768; i += 256) wpL[i] = wproj[i];
    if (tid < 32) { gL[tid] = gamma[tid]; btL[tid] = beta[tid]; }
    int wave = tid >> 6, lane = tid & 63;
    int sub = lane >> 4, l16 = lane & 15;
    int nodeIdx = wave * 4 + sub;
    int n = blockIdx.x * 16 + nodeIdx;
    if (n >= N) n = N - 1;
    int base = rowptr[n], deg = rowptr[n + 1] - base;
    const float4* zb4 = (const float4*)zb;

    // pass 1: per-head max (coalesced)
    float mx0 = -INFINITY, mx1 = -INFINITY, mx2 = -INFINITY, mx3 = -INFINITY;
    for (int j = l16; j < deg; j += 16) {
        float4 zv = zb4[base + j];
        mx0 = fmaxf(mx0, zv.x); mx1 = fmaxf(mx1, zv.y);
        mx2 = fmaxf(mx2, zv.z); mx3 = fmaxf(mx3, zv.w);
    }
#pragma unroll
    for (int off = 1; off < 16; off <<= 1) {
        mx0 = fmaxf(mx0, __shfl_xor(mx0, off));
        mx1 = fmaxf(mx1, __shfl_xor(mx1, off));
        mx2 = fmaxf(mx2, __shfl_xor(mx2, off));
        mx3 = fmaxf(mx3, __shfl_xor(mx3, off));
    }
    if (!isfinite(mx0)) mx0 = 0.f;
    if (!isfinite(mx1)) mx1 = 0.f;
    if (!isfinite(mx2)) mx2 = 0.f;
    if (!isfinite(mx3)) mx3 = 0.f;

    // pass 2: per-head sum
    float s0 = 0.f, s1 = 0.f, s2 = 0.f, s3 = 0.f;
    for (int j = l16; j < deg; j += 16) {
        float4 zv = zb4[base + j];
        s0 += __expf(zv.x - mx0); s1 += __expf(zv.y - mx1);
        s2 += __expf(zv.z - mx2); s3 += __expf(zv.w - mx3);
    }
#pragma unroll
    for (int off = 1; off < 16; off <<= 1) {
        s0 += __shfl_xor(s0, off); s1 += __shfl_xor(s1, off);
        s2 += __shfl_xor(s2, off); s3 += __shfl_xor(s3, off);
    }
    float i0 = 1.f / (s0 + 1e-9f), i1 = 1.f / (s1 + 1e-9f);
    float i2 = 1.f / (s2 + 1e-9f), i3 = 1.f / (s3 + 1e-9f);

    // pass 3: chunked alpha -> LDS, accumulate two comps per lane (x4 unroll)
    int c0 = 2 * l16, c1 = c0 + 1;
    int hA = ((c0 < 8) ? c0 : (c0 - 8) / 3) >> 1;
    int hB = ((c1 < 8) ? c1 : (c1 - 8) / 3) >> 1;
    float accA = 0.f, accB = 0.f;
    for (int j0 = 0; j0 < deg; j0 += 16) {
        int j = j0 + l16;
        float4 a4 = make_float4(0.f, 0.f, 0.f, 0.f);
        if (j < deg) {
            float4 zv = zb4[base + j];
            a4.x = __expf(zv.x - mx0) * i0;
            a4.y = __expf(zv.y - mx1) * i1;
            a4.z = __expf(zv.z - mx2) * i2;
            a4.w = __expf(zv.w - mx3) * i3;
        }
        *(float4*)&aw[nodeIdx][l16][0] = a4;
        __builtin_amdgcn_wave_barrier();
        int cnt = min(16, deg - j0);
        const float* vbase = &vrow[(size_t)(base + j0) * 32 + c0];
        int jj = 0;
        for (; jj + 3 < cnt; jj += 4) {
            float2 v0 = *(const float2*)(vbase + (size_t)jj * 32);
            float2 v1 = *(const float2*)(vbase + (size_t)(jj + 1) * 32);
            float2 v2 = *(const float2*)(vbase + (size_t)(jj + 2) * 32);
            float2 v3 = *(const float2*)(vbase + (size_t)(jj + 3) * 32);
            accA += aw[nodeIdx][jj][hA] * v0.x + aw[nodeIdx][jj + 1][hA] * v1.x +
                    aw[nodeIdx][jj + 2][hA] * v2.x + aw[nodeIdx][jj + 3][hA] * v3.x;
            accB += aw[nodeIdx][jj][hB] * v0.y + aw[nodeIdx][jj + 1][hB] * v1.y +
                    aw[nodeIdx][jj + 2][hB] * v2.y + aw[nodeIdx][jj + 3][hB] * v3.y;
        }
        for (; jj < cnt; ++jj) {
            float2 v = *(const float2*)(vbase + (size_t)jj * 32);
            accA += aw[nodeIdx][jj][hA] * v.x;
            accB += aw[nodeIdx][jj][hB] * v.y;
        }
        __builtin_amdgcn_wave_barrier();
    }

    // stage concat([o, x]) into LDS
    float* in0 = inb[nodeIdx];
    float* in1 = in0 + 24;
    if (c0 < 8) { in0[c0] = accA; in0[c1] = accB; }
    else        { in1[c0 - 8] = accA; in1[c1 - 8] = accB; }
    in0[8 + l16] = xs0[(size_t)n * 16 + l16];
    {
        const float* xp = xs1 + (size_t)n * 48 + l16 * 3;
        in1[24 + l16 * 3 + 0] = xp[0];
        in1[24 + l16 * 3 + 1] = xp[1];
        in1[24 + l16 * 3 + 2] = xp[2];
    }
    __syncthreads();

    // projection: each lane -> 4 outputs of its node
    int c = l16;
    float y0 = 0.f;
#pragma unroll
    for (int j = 0; j < 24; ++j) y0 += in0[j] * wpL[j * 16 + c];
    float y1v[3];
#pragma unroll
    for (int mm = 0; mm < 3; ++mm) {
        float y = 0.f;
#pragma unroll
        for (int j = 0; j < 24; ++j) y += in1[j * 3 + mm] * wpL[384 + j * 16 + c];
        y1v[mm] = y;
    }
    float n0 = sqrtf(y0 * y0 + 1e-12f);
    float n1 = sqrtf(y1v[0] * y1v[0] + y1v[1] * y1v[1] + y1v[2] * y1v[2] + 1e-12f);
    float mu0 = n0, mu1 = n1;
#pragma unroll
    for (int off = 1; off < 16; off <<= 1) {
        mu0 += __shfl_xor(mu0, off);
        mu1 += __shfl_xor(mu1, off);
    }
    mu0 *= 0.0625f; mu1 *= 0.0625f;
    float dv0 = n0 - mu0, dv1 = n1 - mu1;
    float var0 = dv0 * dv0, var1 = dv1 * dv1;
#pragma unroll
    for (int off = 1; off < 16; off <<= 1) {
        var0 += __shfl_xor(var0, off);
        var1 += __shfl_xor(var1, off);
    }
    var0 *= 0.0625f; var1 *= 0.0625f;
    float ln0 = dv0 * rsqrtf(var0 + 1e-5f) * gL[c] + btL[c];
    float ln1 = dv1 * rsqrtf(var1 + 1e-5f) * gL[16 + c] + btL[16 + c];
    float fac0 = fmaxf(ln0, 0.f) / (n0 + 1e-3f);
    float fac1 = fmaxf(ln1, 0.f) / (n1 + 1e-3f);
    float x0n = y0 * fac0;
    float x1n[3] = {y1v[0] * fac1, y1v[1] * fac1, y1v[2] * fac1};
    xs0[(size_t)n * 16 + c] = x0n;
    float* xo = xs1 + (size_t)n * 48 + c * 3;
    xo[0] = x1n[0]; xo[1] = x1n[1]; xo[2] = x1n[2];

    // ---- fused next-layer q: stage normalized x back into inb, then project ----
    if (wq_next) {
        __builtin_amdgcn_wave_barrier();
        in0[8 + c] = x0n;
        in1[24 + c * 3 + 0] = x1n[0];
        in1[24 + c * 3 + 1] = x1n[1];
        in1[24 + c * 3 + 2] = x1n[2];
        __builtin_amdgcn_wave_barrier();
        int compA = 2 * l16, compB = compA + 1;
#pragma unroll
        for (int cb = 0; cb < 2; ++cb) {
            int comp = cb ? compB : compA;
            float a = 0.f;
            if (comp < 8) {
#pragma unroll
                for (int cc = 0; cc < 16; ++cc)
                    a += in0[8 + cc] * wq_next[cc * 8 + comp];
                q0[(size_t)n * 8 + comp] = a;
            } else {
                int idx = comp - 8, dd = idx / 3, mm = idx % 3;
#pragma unroll
                for (int cc = 0; cc < 16; ++cc)
                    a += in1[24 + cc * 3 + mm] * wq_next[128 + cc * 8 + dd];
                q1[(size_t)n * 24 + idx] = a;
            }
        }
    }
}

// ---------------- final output: segment-sum(vrow) + x @ wself ----------------
__global__ __launch_bounds__(256) void k_out(
    int N,
    const int* __restrict__ rowptr, const float* __restrict__ vrow,
    const float* __restrict__ xs0, const float* __restrict__ xs1,
    const float* __restrict__ wself,  // (2,16,8)
    float* __restrict__ out) {
    int tid = threadIdx.x;
    int wave = tid >> 6, lane = tid & 63;
    int sub = lane >> 4, l16 = lane & 15;
    int n = blockIdx.x * 16 + wave * 4 + sub;
    if (n >= N) n = N - 1;
    int base = rowptr[n], deg = rowptr[n + 1] - base;

    int c0 = 2 * l16, c1 = c0 + 1;
    float accA = 0.f, accB = 0.f;
    const float* vbase = &vrow[(size_t)base * 32 + c0];
    int j = 0;
    for (; j + 3 < deg; j += 4) {
        float2 v0 = *(const float2*)(vbase + (size_t)j * 32);
        float2 v1 = *(const float2*)(vbase + (size_t)(j + 1) * 32);
        float2 v2 = *(const float2*)(vbase + (size_t)(j + 2) * 32);
        float2 v3 = *(const float2*)(vbase + (size_t)(j + 3) * 32);
        accA += v0.x + v1.x + v2.x + v3.x;
        accB += v0.y + v1.y + v2.y + v3.y;
    }
    for (; j < deg; ++j) {
        float2 v = *(const float2*)(vbase + (size_t)j * 32);
        accA += v.x;
        accB += v.y;
    }
    if (c0 < 8) {
#pragma unroll
        for (int c = 0; c < 16; ++c) {
            float xv = xs0[(size_t)n * 16 + c];
            accA += xv * wself[c * 8 + c0];
            accB += xv * wself[c * 8 + c1];
        }
    } else {
        int dA = (c0 - 8) / 3, mA = (c0 - 8) % 3;
        int dB = (c1 - 8) / 3, mB = (c1 - 8) % 3;
#pragma unroll
        for (int c = 0; c < 16; ++c) {
            accA += xs1[(size_t)n * 48 + c * 3 + mA] * wself[128 + c * 8 + dA];
            accB += xs1[(size_t)n * 48 + c * 3 + mB] * wself[128 + c * 8 + dB];
        }
    }
    *(float2*)&out[(size_t)n * 32 + c0] = make_float2(accA, accB);
}

// ---------------------------------------------------------------------------
extern "C" void kernel_launch(void* const* d_in, const int* in_sizes, int n_in,
                              void* d_out, int out_size, void* d_ws, size_t ws_size,
                              hipStream_t stream) {
    const float* x0 = (const float*)d_in[0];
    const float* x1 = (const float*)d_in[1];
    const float* ef = (const float*)d_in[2];
    const float* b00 = (const float*)d_in[3];
    const float* b01 = (const float*)d_in[4];
    const float* b10 = (const float*)d_in[5];
    const float* b11 = (const float*)d_in[6];
    const float* kvw1 = (const float*)d_in[7];    // (2,4,16,16)
    const float* kvw2n = (const float*)d_in[8];   // (2,3,16,16,16)
    const float* kvw211 = (const float*)d_in[9];  // (2,16,16,16,3)
    const float* wq = (const float*)d_in[10];     // (2,2,16,8)
    const float* wproj = (const float*)d_in[11];  // (2,2,24,16)
    const float* gam = (const float*)d_in[12];    // (2,2,16)
    const float* bet = (const float*)d_in[13];
    const float* fcw1 = (const float*)d_in[14];    // (4,16,16)
    const float* fcw2n = (const float*)d_in[15];   // (3,16,8,16)
    const float* fcw211 = (const float*)d_in[16];  // (16,8,16,3)
    const float* fcself = (const float*)d_in[17];  // (2,16,8)
    const int* esrc = (const int*)d_in[18];
    const int* edst = (const int*)d_in[19];
    int N = in_sizes[0] / 16;
    int E = in_sizes[18];
    float* out = (float*)d_out;

    float* ws = (float*)d_ws;
    size_t off = 0;
    float* xs0 = ws + off; off += (size_t)N * 16;
    float* xs1 = ws + off; off += (size_t)N * 48;
    float* q0b = ws + off; off += (size_t)N * 8;
    float* q1b = ws + off; off += (size_t)N * 24;
    float* vrow = ws + off; off += (size_t)E * 32;
    float* zb = ws + off; off += (size_t)E * 4;
    int* counts = (int*)(ws + off); off += N;
    int* rowptr = (int*)(ws + off); off += N + 1;
    int* cursor = (int*)(ws + off); off += N;
    int* pose = (int*)(ws + off); off += E;
    off = (off + 3) & ~(size_t)3;
    unsigned short* efh = (unsigned short*)(ws + off); off += (size_t)E * 16 / 2;
    unsigned short* Wfrag = (unsigned short*)(ws + off); off += (size_t)156 * 64 * 8 / 2;

    const int tpb = 256;
    int ebl = (E + 255) / 256;
    int cblk = (E / 16 + 3) / 4;
    int nbl16 = (N + 15) / 16;

    k_prepw<<<(156 * 512 + 255) / 256, tpb, 0, stream>>>(kvw1, fcw1, kvw2n, kvw211,
                                                         fcw2n, fcw211, Wfrag);
    int mtot = N * 64 + E * 16;
    k_misc<<<(mtot + 255) / 256, tpb, 0, stream>>>(x0, x1, ef, xs0, xs1, efh,
                                                   N * 16, N * 48, E * 16);
    hipMemsetAsync(counts, 0, (size_t)N * 4, stream);
    k_hist<<<ebl, tpb, 0, stream>>>(edst, counts, E);
    int CH = (N + 1023) / 1024;
    k_scan<<<1, 1024, 0, stream>>>(counts, rowptr, cursor, N, CH);
    k_scatter<<<ebl, tpb, 0, stream>>>(edst, cursor, pose, E);
    k_q<<<(N * 32 + 255) / 256, tpb, 0, stream>>>(N, xs0, xs1, wq, q0b, q1b);

    // layer 0
    k_conv<16, true><<<cblk, tpb, 0, stream>>>(E, esrc, edst, pose, xs0, xs1,
                                               b00, b01, b10, b11, efh, Wfrag, 0,
                                               q0b, q1b, vrow, zb);
    k_attn<<<nbl16, tpb, 0, stream>>>(N, rowptr, zb, vrow, wproj,
                                      gam, bet, xs0, xs1, wq + 256, q0b, q1b);
    // layer 1
    k_conv<16, true><<<cblk, tpb, 0, stream>>>(E, esrc, edst, pose, xs0, xs1,
                                               b00, b01, b10, b11, efh, Wfrag, 52,
                                               q0b, q1b, vrow, zb);
    k_attn<<<nbl16, tpb, 0, stream>>>(N, rowptr, zb, vrow, wproj + 768,
                                      gam + 32, bet + 32, xs0, xs1, nullptr, q0b, q1b);
    // final conv + output
    k_conv<8, false><<<cblk, tpb, 0, stream>>>(E, esrc, edst, pose, xs0, xs1,
                                               b00, b01, b10, b11, efh, Wfrag, 104,
                                               q0b, q1b, vrow, zb);
    k_out<<<nbl16, tpb, 0, stream>>>(N, rowptr, vrow, xs0, xs1, fcself, out);
}